// Round 4
// baseline (2512.272 us; speedup 1.0000x reference)
//
#include <hip/hip_runtime.h>
#include <hip/hip_bf16.h>
#include <math.h>

// Problem constants
#define Bc 2
#define Tc 1024
#define Dc 512
#define NHc 8
#define Lc 4
#define Ec 8
#define Kc 2
#define Hc 2048
#define HDc 64
#define Nc (Bc * Tc)   // 2048 tokens
#define NKc (Nc * Kc)  // 4096 compact MoE rows

typedef __bf16 bf16x8 __attribute__((ext_vector_type(8)));
typedef float  f32x4  __attribute__((ext_vector_type(4)));
typedef unsigned short ushort8v __attribute__((ext_vector_type(8)));
typedef unsigned short ushort4v __attribute__((ext_vector_type(4)));

__device__ inline unsigned short f2bf(float f) {
    union { float f; unsigned u; } v; v.f = f;
    unsigned r = v.u + 0x7FFFu + ((v.u >> 16) & 1u);   // RNE
    return (unsigned short)(r >> 16);
}
__device__ inline float bf2f(unsigned short b) {
    union { unsigned u; float f; } v; v.u = ((unsigned)b) << 16;
    return v.f;
}
// split a = hi + lo (each bf16); residual ~2^-17 relative
__device__ inline void splitbf(float a, unsigned short& hi, unsigned short& lo) {
    unsigned short h = f2bf(a);
    hi = h;
    lo = f2bf(a - bf2f(h));
}
// split 8 consecutive floats (two float4) into hi/lo ushort8 vectors
__device__ inline void split8(const float4& a, const float4& b,
                              ushort8v& h, ushort8v& l) {
    unsigned short hh, ll;
    splitbf(a.x, hh, ll); h[0] = hh; l[0] = ll;
    splitbf(a.y, hh, ll); h[1] = hh; l[1] = ll;
    splitbf(a.z, hh, ll); h[2] = hh; l[2] = ll;
    splitbf(a.w, hh, ll); h[3] = hh; l[3] = ll;
    splitbf(b.x, hh, ll); h[4] = hh; l[4] = ll;
    splitbf(b.y, hh, ll); h[5] = hh; l[5] = ll;
    splitbf(b.z, hh, ll); h[6] = hh; l[6] = ll;
    splitbf(b.w, hh, ll); h[7] = hh; l[7] = ll;
}

// bijective XCD swizzle (m204): contiguous tile chunks per XCD for L2 reuse
__device__ inline int xcd_swizzle(int orig, int nwg) {
    int q = nwg >> 3, r = nwg & 7;
    int xcd = orig & 7, slot = orig >> 3;
    return (xcd < r ? xcd * (q + 1) : r * (q + 1) + (xcd - r) * q) + slot;
}

// ---------------------------------------------------------------------------
// Weight pre-split: fp32 -> (hi, lo) bf16 ushort arrays.
// ---------------------------------------------------------------------------
__global__ __launch_bounds__(256) void split_w_kernel(
    const float* __restrict__ w, unsigned short* __restrict__ hi,
    unsigned short* __restrict__ lo, int n4)
{
    int i = blockIdx.x * 256 + threadIdx.x;
    if (i >= n4) return;
    float4 v = ((const float4*)w)[i];
    ushort4v h, l;
    unsigned short a, b;
    splitbf(v.x, a, b); h[0] = a; l[0] = b;
    splitbf(v.y, a, b); h[1] = a; l[1] = b;
    splitbf(v.z, a, b); h[2] = a; l[2] = b;
    splitbf(v.w, a, b); h[3] = a; l[3] = b;
    ((ushort4v*)hi)[i] = h;
    ((ushort4v*)lo)[i] = l;
}

// ---------------------------------------------------------------------------
// RMSNorm emitting fp32 (for router) + pre-split hi/lo (for GEMM A-operand)
// ---------------------------------------------------------------------------
__global__ __launch_bounds__(256) void rmsnorm_split_kernel(
    const float* __restrict__ x, const float* __restrict__ w,
    float* __restrict__ y, unsigned short* __restrict__ yh,
    unsigned short* __restrict__ yl)
{
    int row = blockIdx.x;
    const float* xr = x + (size_t)row * Dc;
    __shared__ float red[256];
    int tid = threadIdx.x;
    float ss = 0.0f;
    for (int d = tid; d < Dc; d += 256) { float v = xr[d]; ss += v * v; }
    red[tid] = ss; __syncthreads();
    for (int s = 128; s > 0; s >>= 1) {
        if (tid < s) red[tid] += red[tid + s];
        __syncthreads();
    }
    float inv = rsqrtf(red[0] / (float)Dc + 1e-5f);
    for (int d = tid; d < Dc; d += 256) {
        float v = w[d] * xr[d] * inv;
        size_t idx = (size_t)row * Dc + d;
        y[idx] = v;
        unsigned short h, l;
        splitbf(v, h, l);
        yh[idx] = h; yl[idx] = l;
    }
}

// plain fp32 rmsnorm (final output)
__global__ __launch_bounds__(256) void rmsnorm_kernel(
    const float* __restrict__ x, const float* __restrict__ w,
    float* __restrict__ y)
{
    int row = blockIdx.x;
    const float* xr = x + (size_t)row * Dc;
    __shared__ float red[256];
    int tid = threadIdx.x;
    float ss = 0.0f;
    for (int d = tid; d < Dc; d += 256) { float v = xr[d]; ss += v * v; }
    red[tid] = ss; __syncthreads();
    for (int s = 128; s > 0; s >>= 1) {
        if (tid < s) red[tid] += red[tid + s];
        __syncthreads();
    }
    float inv = rsqrtf(red[0] / (float)Dc + 1e-5f);
    for (int d = tid; d < Dc; d += 256)
        y[(size_t)row * Dc + d] = w[d] * xr[d] * inv;
}

// ---------------------------------------------------------------------------
// bf16x3 MFMA GEMM on PRE-SPLIT operands: C[M,N] (op)= A @ W^T.
// BK=32, 4 waves (2x2), prefetch depth 2 (two named register sets, K-loop
// unrolled x2 -> ~800cy load->use window), XCD-swizzled tile ids, pad-40 LDS.
// Requires K % 64 == 0.
// MODE 0: C =    MODE 1: C +=
// MODE 5: A rows compact [offs..offs+count) (MoE t), W per expert (blockIdx.z),
//         scatter atomicAdd C[tok[r]] += twt[r]*v
// ---------------------------------------------------------------------------
template<int MODE, int TM, int TN>
__global__ __launch_bounds__(256) void gemm3p(
    const unsigned short* __restrict__ Ahi, const unsigned short* __restrict__ Alo,
    const unsigned short* __restrict__ Whibase, const unsigned short* __restrict__ Wlobase,
    float* __restrict__ C, int M, int N, int K,
    const int* __restrict__ tok, const float* __restrict__ twt,
    const int* __restrict__ counts, const int* __restrict__ offsets,
    size_t wstride)
{
    constexpr int PAD = 40;
    constexpr int PA  = TM / 64;
    constexpr int PB  = TN / 64;
    constexpr int FM  = TM / 32;
    constexpr int FN  = TN / 32;

    int e = (MODE == 5) ? blockIdx.z : 0;
    int count = M, offs = 0;
    if (MODE == 5) {
        count = counts[e];
        offs  = offsets[e];
    }
    const unsigned short* Whi = Whibase + (size_t)e * wstride;
    const unsigned short* Wlo = Wlobase + (size_t)e * wstride;

    // XCD-aware tile id
    int nwg  = gridDim.x * gridDim.y;
    int wgid = xcd_swizzle(blockIdx.y * gridDim.x + blockIdx.x, nwg);
    int bx = wgid % gridDim.x, by = wgid / gridDim.x;
    if (MODE == 5 && by * TM >= count) return;

    __shared__ __align__(16) unsigned short Ah[TM][PAD];
    __shared__ __align__(16) unsigned short Al[TM][PAD];
    __shared__ __align__(16) unsigned short Bh[TN][PAD];
    __shared__ __align__(16) unsigned short Bl[TN][PAD];

    int tid = threadIdx.x;
    int m0 = by * TM, n0 = bx * TN;
    int srow = tid >> 2;          // 0..63
    int scol = (tid & 3) * 8;     // 8 elems/thread

    int wave = tid >> 6, lane = tid & 63;
    int wm = wave >> 1, wn = wave & 1;
    int quad = lane >> 4, l16 = lane & 15;

    f32x4 acc[FM][FN];
#pragma unroll
    for (int mi = 0; mi < FM; ++mi)
#pragma unroll
        for (int ni = 0; ni < FN; ++ni)
            acc[mi][ni] = (f32x4){0.f, 0.f, 0.f, 0.f};

    size_t arow[PA];
#pragma unroll
    for (int p = 0; p < PA; ++p) {
        int row = p * 64 + srow;
        if (MODE == 5) {
            int rr = m0 + row; if (rr >= count) rr = 0;
            arow[p] = (size_t)(offs + rr) * K;
        } else {
            arow[p] = (size_t)(m0 + row) * K;
        }
    }
    size_t brow[PB];
#pragma unroll
    for (int p = 0; p < PB; ++p)
        brow[p] = (size_t)(n0 + p * 64 + srow) * K;

#define G3_LOAD(AH, AL, BH, BL, KN)                                       \
    {                                                                     \
        _Pragma("unroll")                                                 \
        for (int p = 0; p < PA; ++p) {                                    \
            AH[p] = *(const ushort8v*)(Ahi + arow[p] + (KN) + scol);      \
            AL[p] = *(const ushort8v*)(Alo + arow[p] + (KN) + scol);      \
        }                                                                 \
        _Pragma("unroll")                                                 \
        for (int p = 0; p < PB; ++p) {                                    \
            BH[p] = *(const ushort8v*)(Whi + brow[p] + (KN) + scol);      \
            BL[p] = *(const ushort8v*)(Wlo + brow[p] + (KN) + scol);      \
        }                                                                 \
    }

#define G3_STORE(AH, AL, BH, BL)                                          \
    {                                                                     \
        _Pragma("unroll")                                                 \
        for (int p = 0; p < PA; ++p) {                                    \
            *(ushort8v*)&Ah[p * 64 + srow][scol] = AH[p];                 \
            *(ushort8v*)&Al[p * 64 + srow][scol] = AL[p];                 \
        }                                                                 \
        _Pragma("unroll")                                                 \
        for (int p = 0; p < PB; ++p) {                                    \
            *(ushort8v*)&Bh[p * 64 + srow][scol] = BH[p];                 \
            *(ushort8v*)&Bl[p * 64 + srow][scol] = BL[p];                 \
        }                                                                 \
    }

#define G3_COMPUTE()                                                      \
    {                                                                     \
        bf16x8 ah[FM], al[FM], bh[FN], bl[FN];                            \
        _Pragma("unroll")                                                 \
        for (int mi = 0; mi < FM; ++mi) {                                 \
            ah[mi] = *(const bf16x8*)&Ah[wm * (TM / 2) + mi * 16 + l16][quad * 8]; \
            al[mi] = *(const bf16x8*)&Al[wm * (TM / 2) + mi * 16 + l16][quad * 8]; \
        }                                                                 \
        _Pragma("unroll")                                                 \
        for (int ni = 0; ni < FN; ++ni) {                                 \
            bh[ni] = *(const bf16x8*)&Bh[wn * (TN / 2) + ni * 16 + l16][quad * 8]; \
            bl[ni] = *(const bf16x8*)&Bl[wn * (TN / 2) + ni * 16 + l16][quad * 8]; \
        }                                                                 \
        _Pragma("unroll")                                                 \
        for (int mi = 0; mi < FM; ++mi)                                   \
            _Pragma("unroll")                                             \
            for (int ni = 0; ni < FN; ++ni) {                             \
                acc[mi][ni] = __builtin_amdgcn_mfma_f32_16x16x32_bf16(    \
                    ah[mi], bh[ni], acc[mi][ni], 0, 0, 0);                \
                acc[mi][ni] = __builtin_amdgcn_mfma_f32_16x16x32_bf16(    \
                    al[mi], bh[ni], acc[mi][ni], 0, 0, 0);                \
                acc[mi][ni] = __builtin_amdgcn_mfma_f32_16x16x32_bf16(    \
                    ah[mi], bl[ni], acc[mi][ni], 0, 0, 0);                \
            }                                                             \
    }

    // two named prefetch sets (static indexing; no scratch)
    ushort8v a0h[PA], a0l[PA], b0h[PB], b0l[PB];
    ushort8v a1h[PA], a1l[PA], b1h[PB], b1l[PB];
    G3_LOAD(a0h, a0l, b0h, b0l, 0)
    G3_LOAD(a1h, a1l, b1h, b1l, 32)

    for (int k0 = 0; k0 < K; k0 += 64) {
        G3_STORE(a0h, a0l, b0h, b0l)
        __syncthreads();
        if (k0 + 64 < K) G3_LOAD(a0h, a0l, b0h, b0l, k0 + 64)
        G3_COMPUTE()
        __syncthreads();
        G3_STORE(a1h, a1l, b1h, b1l)
        __syncthreads();
        if (k0 + 96 < K) G3_LOAD(a1h, a1l, b1h, b1l, k0 + 96)
        G3_COMPUTE()
        __syncthreads();
    }
#undef G3_LOAD
#undef G3_STORE
#undef G3_COMPUTE

#pragma unroll
    for (int mi = 0; mi < FM; ++mi) {
#pragma unroll
        for (int ni = 0; ni < FN; ++ni) {
            int col = n0 + wn * (TN / 2) + ni * 16 + l16;
#pragma unroll
            for (int r = 0; r < 4; ++r) {
                int row = wm * (TM / 2) + mi * 16 + quad * 4 + r;
                float v = acc[mi][ni][r];
                if (MODE == 0) {
                    C[(size_t)(m0 + row) * N + col] = v;
                } else if (MODE == 1) {
                    C[(size_t)(m0 + row) * N + col] += v;
                } else {  // MODE 5
                    int rr = m0 + row;
                    if (rr < count) {
                        int dest = tok[offs + rr];
                        float w = twt[offs + rr];
                        atomicAdd(&C[(size_t)dest * N + col], w * v);
                    }
                }
            }
        }
    }
}

// ---------------------------------------------------------------------------
// Fused FFN up on pre-split operands: t = silu(A@W1^T) * (A@W3^T).
// Emits t PRE-SPLIT (hi/lo).  TM=64 x TN=128, XCD swizzle, PF1.
// GATHER: rows via tok[] (MoE, blockIdx.z=expert, compact output rows).
// ---------------------------------------------------------------------------
template<bool GATHER>
__global__ __launch_bounds__(256) void ffn_fusedp(
    const unsigned short* __restrict__ Ahi, const unsigned short* __restrict__ Alo,
    const unsigned short* __restrict__ W1hibase, const unsigned short* __restrict__ W1lobase,
    const unsigned short* __restrict__ W3hibase, const unsigned short* __restrict__ W3lobase,
    unsigned short* __restrict__ Thi, unsigned short* __restrict__ Tlo,
    int M, int N, int K,
    const int* __restrict__ tok, const int* __restrict__ counts,
    const int* __restrict__ offsets, size_t wstride)
{
    constexpr int TM = 64, TN = 128, PAD = 40;
    constexpr int FM = 2, FN = 4;

    int e = GATHER ? blockIdx.z : 0;
    int count = M, offs = 0;
    if (GATHER) {
        count = counts[e];
        offs  = offsets[e];
    }
    const unsigned short* W1hi = W1hibase + (size_t)e * wstride;
    const unsigned short* W1lo = W1lobase + (size_t)e * wstride;
    const unsigned short* W3hi = W3hibase + (size_t)e * wstride;
    const unsigned short* W3lo = W3lobase + (size_t)e * wstride;

    int nwg  = gridDim.x * gridDim.y;
    int wgid = xcd_swizzle(blockIdx.y * gridDim.x + blockIdx.x, nwg);
    int bx = wgid % gridDim.x, by = wgid / gridDim.x;
    if (GATHER && by * TM >= count) return;

    __shared__ __align__(16) unsigned short Ah[TM][PAD];
    __shared__ __align__(16) unsigned short Al[TM][PAD];
    __shared__ __align__(16) unsigned short B1h[TN][PAD];
    __shared__ __align__(16) unsigned short B1l[TN][PAD];
    __shared__ __align__(16) unsigned short B3h[TN][PAD];
    __shared__ __align__(16) unsigned short B3l[TN][PAD];
    __shared__ int sTok[TM];

    int tid = threadIdx.x;
    int m0 = by * TM, n0 = bx * TN;

    if (GATHER) {
        if (tid < TM) {
            int r = m0 + tid;
            sTok[tid] = (r < count) ? tok[offs + r] : tok[offs];
        }
        __syncthreads();
    }

    int srow = tid >> 2;
    int scol = (tid & 3) * 8;
    int wave = tid >> 6, lane = tid & 63;
    int wm = wave >> 1, wn = wave & 1;
    int quad = lane >> 4, l16 = lane & 15;

    f32x4 accg[FM][FN], accu[FM][FN];
#pragma unroll
    for (int mi = 0; mi < FM; ++mi)
#pragma unroll
        for (int ni = 0; ni < FN; ++ni) {
            accg[mi][ni] = (f32x4){0.f, 0.f, 0.f, 0.f};
            accu[mi][ni] = (f32x4){0.f, 0.f, 0.f, 0.f};
        }

    size_t arow;
    if (GATHER) arow = (size_t)sTok[srow] * K;
    else        arow = (size_t)(m0 + srow) * K;
    size_t brow[2];
    brow[0] = (size_t)(n0 + srow) * K;
    brow[1] = (size_t)(n0 + 64 + srow) * K;

    ushort8v pah, pal, p1h[2], p1l[2], p3h[2], p3l[2];
    pah = *(const ushort8v*)(Ahi + arow + scol);
    pal = *(const ushort8v*)(Alo + arow + scol);
#pragma unroll
    for (int p = 0; p < 2; ++p) {
        p1h[p] = *(const ushort8v*)(W1hi + brow[p] + scol);
        p1l[p] = *(const ushort8v*)(W1lo + brow[p] + scol);
        p3h[p] = *(const ushort8v*)(W3hi + brow[p] + scol);
        p3l[p] = *(const ushort8v*)(W3lo + brow[p] + scol);
    }

    for (int k0 = 0; k0 < K; k0 += 32) {
        *(ushort8v*)&Ah[srow][scol] = pah;
        *(ushort8v*)&Al[srow][scol] = pal;
#pragma unroll
        for (int p = 0; p < 2; ++p) {
            int row = p * 64 + srow;
            *(ushort8v*)&B1h[row][scol] = p1h[p];
            *(ushort8v*)&B1l[row][scol] = p1l[p];
            *(ushort8v*)&B3h[row][scol] = p3h[p];
            *(ushort8v*)&B3l[row][scol] = p3l[p];
        }
        __syncthreads();
        if (k0 + 32 < K) {
            int kn = k0 + 32;
            pah = *(const ushort8v*)(Ahi + arow + kn + scol);
            pal = *(const ushort8v*)(Alo + arow + kn + scol);
#pragma unroll
            for (int p = 0; p < 2; ++p) {
                p1h[p] = *(const ushort8v*)(W1hi + brow[p] + kn + scol);
                p1l[p] = *(const ushort8v*)(W1lo + brow[p] + kn + scol);
                p3h[p] = *(const ushort8v*)(W3hi + brow[p] + kn + scol);
                p3l[p] = *(const ushort8v*)(W3lo + brow[p] + kn + scol);
            }
        }

        bf16x8 ah[FM], al[FM], bh[FN], bl[FN];
#pragma unroll
        for (int mi = 0; mi < FM; ++mi) {
            ah[mi] = *(const bf16x8*)&Ah[wm * 32 + mi * 16 + l16][quad * 8];
            al[mi] = *(const bf16x8*)&Al[wm * 32 + mi * 16 + l16][quad * 8];
        }
        // gate = A @ W1^T
#pragma unroll
        for (int ni = 0; ni < FN; ++ni) {
            bh[ni] = *(const bf16x8*)&B1h[wn * 64 + ni * 16 + l16][quad * 8];
            bl[ni] = *(const bf16x8*)&B1l[wn * 64 + ni * 16 + l16][quad * 8];
        }
#pragma unroll
        for (int mi = 0; mi < FM; ++mi)
#pragma unroll
            for (int ni = 0; ni < FN; ++ni) {
                accg[mi][ni] = __builtin_amdgcn_mfma_f32_16x16x32_bf16(
                    ah[mi], bh[ni], accg[mi][ni], 0, 0, 0);
                accg[mi][ni] = __builtin_amdgcn_mfma_f32_16x16x32_bf16(
                    al[mi], bh[ni], accg[mi][ni], 0, 0, 0);
                accg[mi][ni] = __builtin_amdgcn_mfma_f32_16x16x32_bf16(
                    ah[mi], bl[ni], accg[mi][ni], 0, 0, 0);
            }
        // up = A @ W3^T
#pragma unroll
        for (int ni = 0; ni < FN; ++ni) {
            bh[ni] = *(const bf16x8*)&B3h[wn * 64 + ni * 16 + l16][quad * 8];
            bl[ni] = *(const bf16x8*)&B3l[wn * 64 + ni * 16 + l16][quad * 8];
        }
#pragma unroll
        for (int mi = 0; mi < FM; ++mi)
#pragma unroll
            for (int ni = 0; ni < FN; ++ni) {
                accu[mi][ni] = __builtin_amdgcn_mfma_f32_16x16x32_bf16(
                    ah[mi], bh[ni], accu[mi][ni], 0, 0, 0);
                accu[mi][ni] = __builtin_amdgcn_mfma_f32_16x16x32_bf16(
                    al[mi], bh[ni], accu[mi][ni], 0, 0, 0);
                accu[mi][ni] = __builtin_amdgcn_mfma_f32_16x16x32_bf16(
                    ah[mi], bl[ni], accu[mi][ni], 0, 0, 0);
            }
        __syncthreads();
    }

#pragma unroll
    for (int mi = 0; mi < FM; ++mi) {
#pragma unroll
        for (int ni = 0; ni < FN; ++ni) {
            int col = n0 + wn * 64 + ni * 16 + l16;
#pragma unroll
            for (int r = 0; r < 4; ++r) {
                int row = wm * 32 + mi * 16 + quad * 4 + r;
                float g = accg[mi][ni][r];
                float u = accu[mi][ni][r];
                float t = (g / (1.0f + expf(-g))) * u;
                unsigned short th, tl;
                splitbf(t, th, tl);
                if (GATHER) {
                    int rr = m0 + row;
                    if (rr < count) {
                        size_t idx = (size_t)(offs + rr) * N + col;
                        Thi[idx] = th; Tlo[idx] = tl;
                    }
                } else {
                    size_t idx = (size_t)(m0 + row) * N + col;
                    Thi[idx] = th; Tlo[idx] = tl;
                }
            }
        }
    }
}

// ---------------------------------------------------------------------------
// RoPE in-place over q,k slices of qkv [N, 3*D]
// ---------------------------------------------------------------------------
__global__ __launch_bounds__(256) void rope_kernel(float* __restrict__ qkv)
{
    const int HD2 = HDc / 2;
    int idx = blockIdx.x * blockDim.x + threadIdx.x;
    int total = Nc * NHc * HD2;
    if (idx >= total) return;
    int i = idx % HD2;
    int hh = (idx / HD2) % NHc;
    int n = idx / (HD2 * NHc);
    int t = n % Tc;
    float invf = expf(-(2.0f * (float)i / (float)HDc) * logf(10000.0f));
    float f = (float)t * invf;
    float c = cosf(f), s = sinf(f);
    size_t base = (size_t)n * (3 * Dc) + (size_t)hh * HDc;
    float* qp = qkv + base;
    float* kp = qkv + base + Dc;
    float q1 = qp[i], q2 = qp[i + HD2];
    qp[i]       = q1 * c - q2 * s;
    qp[i + HD2] = q1 * s + q2 * c;
    float k1 = kp[i], k2 = kp[i + HD2];
    kp[i]       = k1 * c - k2 * s;
    kp[i + HD2] = k1 * s + k2 * c;
}

// ---------------------------------------------------------------------------
// MFMA flash attention, bf16x3 precision.  Emits output PRE-SPLIT (hi/lo)
// for the out-projection GEMM.
// ---------------------------------------------------------------------------
__global__ __launch_bounds__(256) void attn_mfma(
    const float* __restrict__ qkv, unsigned short* __restrict__ outh,
    unsigned short* __restrict__ outl)
{
    constexpr int PAD = 72;
    __shared__ __align__(16) unsigned short Qh[64][PAD];
    __shared__ __align__(16) unsigned short Ql[64][PAD];
    __shared__ __align__(16) unsigned short Kh[64][PAD];   // aliased: P-hi
    __shared__ __align__(16) unsigned short Kl[64][PAD];   // aliased: P-lo
    __shared__ __align__(16) unsigned short Vth[64][PAD];  // V^T [hd][kv]
    __shared__ __align__(16) unsigned short Vtl[64][PAD];

    int qb = blockIdx.x, bh = blockIdx.y;
    int b = bh >> 3, hh = bh & 7;
    const int D3 = 3 * Dc;
    const float* base = qkv + (size_t)b * Tc * D3 + (size_t)hh * HDc;

    int tid = threadIdx.x;
    int wave = tid >> 6, lane = tid & 63;
    int quad = lane >> 4, l16 = lane & 15;

    int srow = tid >> 2;
    int scb  = (tid & 3) * 16;
    int vhd  = lane;
    int vkb  = wave * 16;

    {
        const float* qp = base + (size_t)(qb * 64 + srow) * D3 + scb;
        float4 q0 = *(const float4*)(qp);
        float4 q1 = *(const float4*)(qp + 4);
        float4 q2 = *(const float4*)(qp + 8);
        float4 q3 = *(const float4*)(qp + 12);
        const float sc = 0.125f;
        q0.x *= sc; q0.y *= sc; q0.z *= sc; q0.w *= sc;
        q1.x *= sc; q1.y *= sc; q1.z *= sc; q1.w *= sc;
        q2.x *= sc; q2.y *= sc; q2.z *= sc; q2.w *= sc;
        q3.x *= sc; q3.y *= sc; q3.z *= sc; q3.w *= sc;
        ushort8v h, l;
        split8(q0, q1, h, l);
        *(ushort8v*)&Qh[srow][scb]     = h;
        *(ushort8v*)&Ql[srow][scb]     = l;
        split8(q2, q3, h, l);
        *(ushort8v*)&Qh[srow][scb + 8] = h;
        *(ushort8v*)&Ql[srow][scb + 8] = l;
    }
    __syncthreads();
    bf16x8 qah[2], qal[2];
#pragma unroll
    for (int ks = 0; ks < 2; ++ks) {
        qah[ks] = *(const bf16x8*)&Qh[wave * 16 + l16][ks * 32 + quad * 8];
        qal[ks] = *(const bf16x8*)&Ql[wave * 16 + l16][ks * 32 + quad * 8];
    }

    float4 kf0, kf1, kf2, kf3;
    float vf[16];
    {
        const float* kp = base + (size_t)srow * D3 + Dc + scb;
        kf0 = *(const float4*)(kp);
        kf1 = *(const float4*)(kp + 4);
        kf2 = *(const float4*)(kp + 8);
        kf3 = *(const float4*)(kp + 12);
        const float* vp = base + (size_t)vkb * D3 + 2 * Dc + vhd;
#pragma unroll
        for (int i = 0; i < 16; ++i) vf[i] = vp[(size_t)i * D3];
    }

    f32x4 o[4];
#pragma unroll
    for (int f = 0; f < 4; ++f) o[f] = (f32x4){0.f, 0.f, 0.f, 0.f};
    float mrow[4], lrow[4];
#pragma unroll
    for (int r = 0; r < 4; ++r) { mrow[r] = -1e30f; lrow[r] = 0.0f; }

    for (int kt = 0; kt <= qb; ++kt) {
        __syncthreads();
        {
            ushort8v h, l;
            split8(kf0, kf1, h, l);
            *(ushort8v*)&Kh[srow][scb]     = h;
            *(ushort8v*)&Kl[srow][scb]     = l;
            split8(kf2, kf3, h, l);
            *(ushort8v*)&Kh[srow][scb + 8] = h;
            *(ushort8v*)&Kl[srow][scb + 8] = l;
        }
        {
            float4 v0 = make_float4(vf[0], vf[1], vf[2], vf[3]);
            float4 v1 = make_float4(vf[4], vf[5], vf[6], vf[7]);
            float4 v2 = make_float4(vf[8], vf[9], vf[10], vf[11]);
            float4 v3 = make_float4(vf[12], vf[13], vf[14], vf[15]);
            ushort8v h, l;
            split8(v0, v1, h, l);
            *(ushort8v*)&Vth[vhd][vkb]     = h;
            *(ushort8v*)&Vtl[vhd][vkb]     = l;
            split8(v2, v3, h, l);
            *(ushort8v*)&Vth[vhd][vkb + 8] = h;
            *(ushort8v*)&Vtl[vhd][vkb + 8] = l;
        }
        __syncthreads();
        if (kt < qb) {
            const float* kp = base + (size_t)((kt + 1) * 64 + srow) * D3 + Dc + scb;
            kf0 = *(const float4*)(kp);
            kf1 = *(const float4*)(kp + 4);
            kf2 = *(const float4*)(kp + 8);
            kf3 = *(const float4*)(kp + 12);
            const float* vp = base + (size_t)((kt + 1) * 64 + vkb) * D3 + 2 * Dc + vhd;
#pragma unroll
            for (int i = 0; i < 16; ++i) vf[i] = vp[(size_t)i * D3];
        }

        f32x4 s[4];
#pragma unroll
        for (int ni = 0; ni < 4; ++ni) s[ni] = (f32x4){0.f, 0.f, 0.f, 0.f};
#pragma unroll
        for (int ks = 0; ks < 2; ++ks) {
            bf16x8 kh_[4], kl_[4];
#pragma unroll
            for (int ni = 0; ni < 4; ++ni) {
                kh_[ni] = *(const bf16x8*)&Kh[ni * 16 + l16][ks * 32 + quad * 8];
                kl_[ni] = *(const bf16x8*)&Kl[ni * 16 + l16][ks * 32 + quad * 8];
            }
#pragma unroll
            for (int ni = 0; ni < 4; ++ni) {
                s[ni] = __builtin_amdgcn_mfma_f32_16x16x32_bf16(
                    qah[ks], kh_[ni], s[ni], 0, 0, 0);
                s[ni] = __builtin_amdgcn_mfma_f32_16x16x32_bf16(
                    qal[ks], kh_[ni], s[ni], 0, 0, 0);
                s[ni] = __builtin_amdgcn_mfma_f32_16x16x32_bf16(
                    qah[ks], kl_[ni], s[ni], 0, 0, 0);
            }
        }

        if (kt == qb) {
#pragma unroll
            for (int ni = 0; ni < 4; ++ni)
#pragma unroll
                for (int r = 0; r < 4; ++r)
                    if (ni * 16 + l16 > wave * 16 + quad * 4 + r)
                        s[ni][r] = -1e30f;
        }

        float al4[4];
#pragma unroll
        for (int r = 0; r < 4; ++r) {
            float rm = fmaxf(fmaxf(s[0][r], s[1][r]), fmaxf(s[2][r], s[3][r]));
            rm = fmaxf(rm, __shfl_xor(rm, 1));
            rm = fmaxf(rm, __shfl_xor(rm, 2));
            rm = fmaxf(rm, __shfl_xor(rm, 4));
            rm = fmaxf(rm, __shfl_xor(rm, 8));
            float mn = fmaxf(mrow[r], rm);
            al4[r] = __expf(mrow[r] - mn);
            mrow[r] = mn;
            float rs = 0.0f;
#pragma unroll
            for (int ni = 0; ni < 4; ++ni) {
                float pv = __expf(s[ni][r] - mn);
                s[ni][r] = pv;
                rs += pv;
            }
            rs += __shfl_xor(rs, 1);
            rs += __shfl_xor(rs, 2);
            rs += __shfl_xor(rs, 4);
            rs += __shfl_xor(rs, 8);
            lrow[r] = lrow[r] * al4[r] + rs;
        }

        __syncthreads();
#pragma unroll
        for (int ni = 0; ni < 4; ++ni)
#pragma unroll
            for (int r = 0; r < 4; ++r) {
                unsigned short hp, lp;
                splitbf(s[ni][r], hp, lp);
                Kh[wave * 16 + quad * 4 + r][ni * 16 + l16] = hp;
                Kl[wave * 16 + quad * 4 + r][ni * 16 + l16] = lp;
            }
#pragma unroll
        for (int f = 0; f < 4; ++f)
#pragma unroll
            for (int r = 0; r < 4; ++r)
                o[f][r] *= al4[r];
#pragma unroll
        for (int ks = 0; ks < 2; ++ks) {
            bf16x8 pah = *(const bf16x8*)&Kh[wave * 16 + l16][ks * 32 + quad * 8];
            bf16x8 pal = *(const bf16x8*)&Kl[wave * 16 + l16][ks * 32 + quad * 8];
#pragma unroll
            for (int f = 0; f < 4; ++f) {
                bf16x8 vh_ = *(const bf16x8*)&Vth[f * 16 + l16][ks * 32 + quad * 8];
                bf16x8 vl_ = *(const bf16x8*)&Vtl[f * 16 + l16][ks * 32 + quad * 8];
                o[f] = __builtin_amdgcn_mfma_f32_16x16x32_bf16(
                    pah, vh_, o[f], 0, 0, 0);
                o[f] = __builtin_amdgcn_mfma_f32_16x16x32_bf16(
                    pal, vh_, o[f], 0, 0, 0);
                o[f] = __builtin_amdgcn_mfma_f32_16x16x32_bf16(
                    pah, vl_, o[f], 0, 0, 0);
            }
        }
    }

#pragma unroll
    for (int r = 0; r < 4; ++r) {
        float inv = 1.0f / lrow[r];
        int q = qb * 64 + wave * 16 + quad * 4 + r;
#pragma unroll
        for (int f = 0; f < 4; ++f) {
            size_t idx = (size_t)(b * Tc + q) * Dc + hh * HDc + f * 16 + l16;
            unsigned short hp, lp;
            splitbf(o[f][r] * inv, hp, lp);
            outh[idx] = hp; outl[idx] = lp;
        }
    }
}

// ---------------------------------------------------------------------------
// Router logits: one wave per token
// ---------------------------------------------------------------------------
__global__ __launch_bounds__(64) void router_kernel(
    const float* __restrict__ x, const float* __restrict__ rw,
    float* __restrict__ logits)
{
    int n = blockIdx.x;
    int lane = threadIdx.x;
    const float* xr = x + (size_t)n * Dc;
    for (int e = 0; e < Ec; ++e) {
        const float* wr = rw + (size_t)e * Dc;
        float p = 0.0f;
        for (int d = lane; d < Dc; d += 64) p += xr[d] * wr[d];
        for (int off = 32; off > 0; off >>= 1) p += __shfl_down(p, off);
        if (lane == 0) logits[(size_t)n * Ec + e] = p;
    }
}

__global__ void zero8_kernel(int* __restrict__ counts)
{
    if (threadIdx.x < Ec) counts[threadIdx.x] = 0;
}

__global__ __launch_bounds__(256) void topk_count_kernel(
    const float* __restrict__ logits, int* __restrict__ counts,
    int2* __restrict__ eidx, float2* __restrict__ ewt)
{
    int n = blockIdx.x * blockDim.x + threadIdx.x;
    if (n >= Nc) return;
    const float* lg = logits + (size_t)n * Ec;
    int i0 = -1, i1 = -1;
    float v0 = -1e30f, v1 = -1e30f;
    for (int e = 0; e < Ec; ++e) {
        float v = lg[e];
        if (v > v0) { v1 = v0; i1 = i0; v0 = v; i0 = e; }
        else if (v > v1) { v1 = v; i1 = e; }
    }
    float e1 = expf(v1 - v0);
    float w0 = 1.0f / (1.0f + e1);
    float w1 = e1 / (1.0f + e1);
    atomicAdd(&counts[i0], 1);
    atomicAdd(&counts[i1], 1);
    eidx[n] = make_int2(i0, i1);
    ewt[n]  = make_float2(w0, w1);
}

__global__ void scan_kernel(int* __restrict__ counts, int* __restrict__ offsets)
{
    if (threadIdx.x == 0) {
        int s = 0;
        for (int e = 0; e < Ec; ++e) { offsets[e] = s; s += counts[e]; counts[e] = 0; }
    }
}

__global__ __launch_bounds__(256) void topk_place_kernel(
    const int2* __restrict__ eidx, const float2* __restrict__ ewt,
    int* __restrict__ counts, const int* __restrict__ offsets,
    int* __restrict__ tok, float* __restrict__ twt)
{
    int n = blockIdx.x * blockDim.x + threadIdx.x;
    if (n >= Nc) return;
    int2 ei = eidx[n];
    float2 w = ewt[n];
    int p0 = atomicAdd(&counts[ei.x], 1);
    int r0 = offsets[ei.x] + p0;
    tok[r0] = n; twt[r0] = w.x;
    int p1 = atomicAdd(&counts[ei.y], 1);
    int r1 = offsets[ei.y] + p1;
    tok[r1] = n; twt[r1] = w.y;
}

// ---------------------------------------------------------------------------
// Host-side orchestration
// ---------------------------------------------------------------------------
extern "C" void kernel_launch(void* const* d_in, const int* in_sizes, int n_in,
                              void* d_out, int out_size, void* d_ws, size_t ws_size,
                              hipStream_t stream)
{
    const float* x        = (const float*)d_in[0];
    const float* qkv_w    = (const float*)d_in[1];
    const float* out_w    = (const float*)d_in[2];
    const float* norm1_w  = (const float*)d_in[3];
    const float* norm2_w  = (const float*)d_in[4];
    const float* router_w = (const float*)d_in[5];
    const float* moe_w1   = (const float*)d_in[6];
    const float* moe_w2   = (const float*)d_in[7];
    const float* moe_w3   = (const float*)d_in[8];
    const float* f_w1     = (const float*)d_in[9];
    const float* f_w2     = (const float*)d_in[10];
    const float* f_w3     = (const float*)d_in[11];
    const float* norm_f   = (const float*)d_in[12];
    float* out = (float*)d_out;

    // workspace (~118 MB)
    float* p = (float*)d_ws;
    float* h      = p;  p += Nc * Dc;
    float* xn     = p;  p += Nc * Dc;
    unsigned short* xnh = (unsigned short*)p;  p += Nc * Dc / 2;
    unsigned short* xnl = (unsigned short*)p;  p += Nc * Dc / 2;
    float* arena  = p;  p += (size_t)NKc * Hc;   // qkv fp32 OR t hi+lo
    float* logits = p;  p += Nc * Ec;
    int*   counts  = (int*)p;  p += 16;
    int*   offsets = (int*)p;  p += 16;
    int2*  eidx    = (int2*)p; p += 2 * Nc;
    float* ewt     = p;        p += 2 * Nc;
    int*   tok     = (int*)p;  p += NKc;
    float* twt     = p;        p += NKc;
    // pre-split weight buffers (ushort counts)
    unsigned short* wqh = (unsigned short*)p;
    unsigned short* wql = wqh + (size_t)3 * Dc * Dc;
    unsigned short* woh = wql + (size_t)3 * Dc * Dc;
    unsigned short* wol = woh + (size_t)Dc * Dc;
    unsigned short* wah = wol + (size_t)Dc * Dc;          // w1 / later w2
    unsigned short* wal = wah + (size_t)Ec * Hc * Dc;
    unsigned short* wbh = wal + (size_t)Ec * Hc * Dc;     // w3
    unsigned short* wbl = wbh + (size_t)Ec * Hc * Dc;

    float* qkv = arena;                         // [Nc][3*Dc] fp32, attn phase
    unsigned short* th = (unsigned short*)arena;         // t hi, FFN phase
    unsigned short* tl = th + (size_t)NKc * Hc;          // t lo

    hipMemcpyAsync(h, x, (size_t)Nc * Dc * sizeof(float),
                   hipMemcpyDeviceToDevice, stream);

    for (int l = 0; l < Lc; ++l) {
        // --- attention block ---
        {
            int n4 = 3 * Dc * Dc / 4;
            split_w_kernel<<<(n4 + 255) / 256, 256, 0, stream>>>(
                qkv_w + (size_t)l * 3 * Dc * Dc, wqh, wql, n4);
        }
        rmsnorm_split_kernel<<<Nc, 256, 0, stream>>>(
            h, norm1_w + (size_t)l * Dc, xn, xnh, xnl);
        gemm3p<0, 64, 128><<<dim3(3 * Dc / 128, Nc / 64, 1), 256, 0, stream>>>(
            xnh, xnl, wqh, wql, qkv, Nc, 3 * Dc, Dc,
            nullptr, nullptr, nullptr, nullptr, 0);
        {
            int total = Nc * NHc * (HDc / 2);
            rope_kernel<<<(total + 255) / 256, 256, 0, stream>>>(qkv);
        }
        {
            int n4 = Dc * Dc / 4;
            split_w_kernel<<<(n4 + 255) / 256, 256, 0, stream>>>(
                out_w + (size_t)l * Dc * Dc, woh, wol, n4);
        }
        attn_mfma<<<dim3(Tc / 64, Bc * NHc), 256, 0, stream>>>(qkv, xnh, xnl);
        gemm3p<1, 64, 64><<<dim3(Dc / 64, Nc / 64, 1), 256, 0, stream>>>(
            xnh, xnl, woh, wol, h, Nc, Dc, Dc,
            nullptr, nullptr, nullptr, nullptr, 0);

        // --- FFN block ---
        rmsnorm_split_kernel<<<Nc, 256, 0, stream>>>(
            h, norm2_w + (size_t)l * Dc, xn, xnh, xnl);
        if (l == 0 || l == 2) {
            int m = l / 2;
            router_kernel<<<Nc, 64, 0, stream>>>(
                xn, router_w + (size_t)m * Ec * Dc, logits);
            zero8_kernel<<<1, 64, 0, stream>>>(counts);
            topk_count_kernel<<<Nc / 256, 256, 0, stream>>>(
                logits, counts, eidx, (float2*)ewt);
            scan_kernel<<<1, 64, 0, stream>>>(counts, offsets);
            topk_place_kernel<<<Nc / 256, 256, 0, stream>>>(
                eidx, (float2*)ewt, counts, offsets, tok, twt);

            int n4 = Ec * Hc * Dc / 4;
            split_w_kernel<<<(n4 + 255) / 256, 256, 0, stream>>>(
                moe_w1 + (size_t)m * Ec * Hc * Dc, wah, wal, n4);
            split_w_kernel<<<(n4 + 255) / 256, 256, 0, stream>>>(
                moe_w3 + (size_t)m * Ec * Hc * Dc, wbh, wbl, n4);
            ffn_fusedp<true><<<dim3(Hc / 128, NKc / 64, Ec), 256, 0, stream>>>(
                xnh, xnl, wah, wal, wbh, wbl, th, tl, Nc, Hc, Dc,
                tok, counts, offsets, (size_t)Hc * Dc);
            split_w_kernel<<<(n4 + 255) / 256, 256, 0, stream>>>(
                moe_w2 + (size_t)m * Ec * Dc * Hc, wah, wal, n4);
            gemm3p<5, 64, 128><<<dim3(Dc / 128, NKc / 64, Ec), 256, 0, stream>>>(
                th, tl, wah, wal, h, Nc, Dc, Hc,
                tok, twt, counts, offsets, (size_t)Dc * Hc);
        } else {
            int m = (l - 1) / 2;
            int n4 = Hc * Dc / 4;
            split_w_kernel<<<(n4 + 255) / 256, 256, 0, stream>>>(
                f_w1 + (size_t)m * Hc * Dc, wah, wal, n4);
            split_w_kernel<<<(n4 + 255) / 256, 256, 0, stream>>>(
                f_w3 + (size_t)m * Hc * Dc, wbh, wbl, n4);
            ffn_fusedp<false><<<dim3(Hc / 128, Nc / 64, 1), 256, 0, stream>>>(
                xnh, xnl, wah, wal, wbh, wbl, th, tl, Nc, Hc, Dc,
                nullptr, nullptr, nullptr, 0);
            split_w_kernel<<<(n4 + 255) / 256, 256, 0, stream>>>(
                f_w2 + (size_t)m * Dc * Hc, wah, wal, n4);
            gemm3p<1, 64, 128><<<dim3(Dc / 128, Nc / 64, 1), 256, 0, stream>>>(
                th, tl, wah, wal, h, Nc, Dc, Hc,
                nullptr, nullptr, nullptr, nullptr, 0);
        }
    }

    rmsnorm_kernel<<<Nc, 256, 0, stream>>>(h, norm_f, out);
}

// Round 5
// 1308.308 us; speedup vs baseline: 1.9202x; 1.9202x over previous
//
#include <hip/hip_runtime.h>
#include <hip/hip_bf16.h>
#include <math.h>

// Problem constants
#define Bc 2
#define Tc 1024
#define Dc 512
#define NHc 8
#define Lc 4
#define Ec 8
#define Kc 2
#define Hc 2048
#define HDc 64
#define Nc (Bc * Tc)   // 2048 tokens
#define NKc (Nc * Kc)  // 4096 compact MoE rows

typedef __bf16 bf16x8 __attribute__((ext_vector_type(8)));
typedef float  f32x4  __attribute__((ext_vector_type(4)));
typedef unsigned short ushort8v __attribute__((ext_vector_type(8)));
typedef unsigned short ushort4v __attribute__((ext_vector_type(4)));

__device__ inline unsigned short f2bf(float f) {
    union { float f; unsigned u; } v; v.f = f;
    unsigned r = v.u + 0x7FFFu + ((v.u >> 16) & 1u);   // RNE
    return (unsigned short)(r >> 16);
}
__device__ inline float bf2f(unsigned short b) {
    union { unsigned u; float f; } v; v.u = ((unsigned)b) << 16;
    return v.f;
}
// split a = hi + lo (each bf16); residual ~2^-17 relative
__device__ inline void splitbf(float a, unsigned short& hi, unsigned short& lo) {
    unsigned short h = f2bf(a);
    hi = h;
    lo = f2bf(a - bf2f(h));
}
// split 8 consecutive floats (two float4) into hi/lo ushort8 vectors
__device__ inline void split8(const float4& a, const float4& b,
                              ushort8v& h, ushort8v& l) {
    unsigned short hh, ll;
    splitbf(a.x, hh, ll); h[0] = hh; l[0] = ll;
    splitbf(a.y, hh, ll); h[1] = hh; l[1] = ll;
    splitbf(a.z, hh, ll); h[2] = hh; l[2] = ll;
    splitbf(a.w, hh, ll); h[3] = hh; l[3] = ll;
    splitbf(b.x, hh, ll); h[4] = hh; l[4] = ll;
    splitbf(b.y, hh, ll); h[5] = hh; l[5] = ll;
    splitbf(b.z, hh, ll); h[6] = hh; l[6] = ll;
    splitbf(b.w, hh, ll); h[7] = hh; l[7] = ll;
}

// ---------------------------------------------------------------------------
// Weight pre-split: fp32 -> (hi, lo) bf16 ushort arrays.
// ---------------------------------------------------------------------------
__global__ __launch_bounds__(256) void split_w_kernel(
    const float* __restrict__ w, unsigned short* __restrict__ hi,
    unsigned short* __restrict__ lo, int n4)
{
    int i = blockIdx.x * 256 + threadIdx.x;
    if (i >= n4) return;
    float4 v = ((const float4*)w)[i];
    ushort4v h, l;
    unsigned short a, b;
    splitbf(v.x, a, b); h[0] = a; l[0] = b;
    splitbf(v.y, a, b); h[1] = a; l[1] = b;
    splitbf(v.z, a, b); h[2] = a; l[2] = b;
    splitbf(v.w, a, b); h[3] = a; l[3] = b;
    ((ushort4v*)hi)[i] = h;
    ((ushort4v*)lo)[i] = l;
}

// ---------------------------------------------------------------------------
// RMSNorm emitting fp32 (for router) + pre-split hi/lo (for GEMM A-operand)
// ---------------------------------------------------------------------------
__global__ __launch_bounds__(256) void rmsnorm_split_kernel(
    const float* __restrict__ x, const float* __restrict__ w,
    float* __restrict__ y, unsigned short* __restrict__ yh,
    unsigned short* __restrict__ yl)
{
    int row = blockIdx.x;
    const float* xr = x + (size_t)row * Dc;
    __shared__ float red[256];
    int tid = threadIdx.x;
    float ss = 0.0f;
    for (int d = tid; d < Dc; d += 256) { float v = xr[d]; ss += v * v; }
    red[tid] = ss; __syncthreads();
    for (int s = 128; s > 0; s >>= 1) {
        if (tid < s) red[tid] += red[tid + s];
        __syncthreads();
    }
    float inv = rsqrtf(red[0] / (float)Dc + 1e-5f);
    for (int d = tid; d < Dc; d += 256) {
        float v = w[d] * xr[d] * inv;
        size_t idx = (size_t)row * Dc + d;
        y[idx] = v;
        unsigned short h, l;
        splitbf(v, h, l);
        yh[idx] = h; yl[idx] = l;
    }
}

// plain fp32 rmsnorm (final output)
__global__ __launch_bounds__(256) void rmsnorm_kernel(
    const float* __restrict__ x, const float* __restrict__ w,
    float* __restrict__ y)
{
    int row = blockIdx.x;
    const float* xr = x + (size_t)row * Dc;
    __shared__ float red[256];
    int tid = threadIdx.x;
    float ss = 0.0f;
    for (int d = tid; d < Dc; d += 256) { float v = xr[d]; ss += v * v; }
    red[tid] = ss; __syncthreads();
    for (int s = 128; s > 0; s >>= 1) {
        if (tid < s) red[tid] += red[tid + s];
        __syncthreads();
    }
    float inv = rsqrtf(red[0] / (float)Dc + 1e-5f);
    for (int d = tid; d < Dc; d += 256)
        y[(size_t)row * Dc + d] = w[d] * xr[d] * inv;
}

// ---------------------------------------------------------------------------
// bf16x3 MFMA GEMM on PRE-SPLIT operands: C[M,N] (op)= A @ W^T.
// BK=32, 4 waves (2x2), prefetch depth 2 (two named register sets, K-loop
// unrolled x2 -> ~800cy load->use window), pad-40 LDS.  Requires K % 64 == 0.
// NOTE: no XCD swizzle — with MoE early-return it concentrates all active
// tiles onto one XCD (r3 post-mortem: 4x regression).
// MODE 0: C =    MODE 1: C +=
// MODE 5: A rows compact [offs..offs+count) (MoE t), W per expert (blockIdx.z),
//         scatter atomicAdd C[tok[r]] += twt[r]*v
// ---------------------------------------------------------------------------
template<int MODE, int TM, int TN>
__global__ __launch_bounds__(256) void gemm3p(
    const unsigned short* __restrict__ Ahi, const unsigned short* __restrict__ Alo,
    const unsigned short* __restrict__ Whibase, const unsigned short* __restrict__ Wlobase,
    float* __restrict__ C, int M, int N, int K,
    const int* __restrict__ tok, const float* __restrict__ twt,
    const int* __restrict__ counts, const int* __restrict__ offsets,
    size_t wstride)
{
    constexpr int PAD = 40;
    constexpr int PA  = TM / 64;
    constexpr int PB  = TN / 64;
    constexpr int FM  = TM / 32;
    constexpr int FN  = TN / 32;

    int e = (MODE == 5) ? blockIdx.z : 0;
    int count = M, offs = 0;
    if (MODE == 5) {
        count = counts[e];
        offs  = offsets[e];
        if ((int)(blockIdx.y * TM) >= count) return;
    }
    const unsigned short* Whi = Whibase + (size_t)e * wstride;
    const unsigned short* Wlo = Wlobase + (size_t)e * wstride;

    __shared__ __align__(16) unsigned short Ah[TM][PAD];
    __shared__ __align__(16) unsigned short Al[TM][PAD];
    __shared__ __align__(16) unsigned short Bh[TN][PAD];
    __shared__ __align__(16) unsigned short Bl[TN][PAD];

    int tid = threadIdx.x;
    int m0 = blockIdx.y * TM, n0 = blockIdx.x * TN;
    int srow = tid >> 2;          // 0..63
    int scol = (tid & 3) * 8;     // 8 elems/thread

    int wave = tid >> 6, lane = tid & 63;
    int wm = wave >> 1, wn = wave & 1;
    int quad = lane >> 4, l16 = lane & 15;

    f32x4 acc[FM][FN];
#pragma unroll
    for (int mi = 0; mi < FM; ++mi)
#pragma unroll
        for (int ni = 0; ni < FN; ++ni)
            acc[mi][ni] = (f32x4){0.f, 0.f, 0.f, 0.f};

    size_t arow[PA];
#pragma unroll
    for (int p = 0; p < PA; ++p) {
        int row = p * 64 + srow;
        if (MODE == 5) {
            int rr = m0 + row; if (rr >= count) rr = 0;
            arow[p] = (size_t)(offs + rr) * K;
        } else {
            arow[p] = (size_t)(m0 + row) * K;
        }
    }
    size_t brow[PB];
#pragma unroll
    for (int p = 0; p < PB; ++p)
        brow[p] = (size_t)(n0 + p * 64 + srow) * K;

#define G3_LOAD(AH, AL, BH, BL, KN)                                       \
    {                                                                     \
        _Pragma("unroll")                                                 \
        for (int p = 0; p < PA; ++p) {                                    \
            AH[p] = *(const ushort8v*)(Ahi + arow[p] + (KN) + scol);      \
            AL[p] = *(const ushort8v*)(Alo + arow[p] + (KN) + scol);      \
        }                                                                 \
        _Pragma("unroll")                                                 \
        for (int p = 0; p < PB; ++p) {                                    \
            BH[p] = *(const ushort8v*)(Whi + brow[p] + (KN) + scol);      \
            BL[p] = *(const ushort8v*)(Wlo + brow[p] + (KN) + scol);      \
        }                                                                 \
    }

#define G3_STORE(AH, AL, BH, BL)                                          \
    {                                                                     \
        _Pragma("unroll")                                                 \
        for (int p = 0; p < PA; ++p) {                                    \
            *(ushort8v*)&Ah[p * 64 + srow][scol] = AH[p];                 \
            *(ushort8v*)&Al[p * 64 + srow][scol] = AL[p];                 \
        }                                                                 \
        _Pragma("unroll")                                                 \
        for (int p = 0; p < PB; ++p) {                                    \
            *(ushort8v*)&Bh[p * 64 + srow][scol] = BH[p];                 \
            *(ushort8v*)&Bl[p * 64 + srow][scol] = BL[p];                 \
        }                                                                 \
    }

#define G3_COMPUTE()                                                      \
    {                                                                     \
        bf16x8 ah[FM], al[FM], bh[FN], bl[FN];                            \
        _Pragma("unroll")                                                 \
        for (int mi = 0; mi < FM; ++mi) {                                 \
            ah[mi] = *(const bf16x8*)&Ah[wm * (TM / 2) + mi * 16 + l16][quad * 8]; \
            al[mi] = *(const bf16x8*)&Al[wm * (TM / 2) + mi * 16 + l16][quad * 8]; \
        }                                                                 \
        _Pragma("unroll")                                                 \
        for (int ni = 0; ni < FN; ++ni) {                                 \
            bh[ni] = *(const bf16x8*)&Bh[wn * (TN / 2) + ni * 16 + l16][quad * 8]; \
            bl[ni] = *(const bf16x8*)&Bl[wn * (TN / 2) + ni * 16 + l16][quad * 8]; \
        }                                                                 \
        _Pragma("unroll")                                                 \
        for (int mi = 0; mi < FM; ++mi)                                   \
            _Pragma("unroll")                                             \
            for (int ni = 0; ni < FN; ++ni) {                             \
                acc[mi][ni] = __builtin_amdgcn_mfma_f32_16x16x32_bf16(    \
                    ah[mi], bh[ni], acc[mi][ni], 0, 0, 0);                \
                acc[mi][ni] = __builtin_amdgcn_mfma_f32_16x16x32_bf16(    \
                    al[mi], bh[ni], acc[mi][ni], 0, 0, 0);                \
                acc[mi][ni] = __builtin_amdgcn_mfma_f32_16x16x32_bf16(    \
                    ah[mi], bl[ni], acc[mi][ni], 0, 0, 0);                \
            }                                                             \
    }

    // two named prefetch sets (static indexing; no scratch)
    ushort8v a0h[PA], a0l[PA], b0h[PB], b0l[PB];
    ushort8v a1h[PA], a1l[PA], b1h[PB], b1l[PB];
    G3_LOAD(a0h, a0l, b0h, b0l, 0)
    G3_LOAD(a1h, a1l, b1h, b1l, 32)

    for (int k0 = 0; k0 < K; k0 += 64) {
        G3_STORE(a0h, a0l, b0h, b0l)
        __syncthreads();
        if (k0 + 64 < K) G3_LOAD(a0h, a0l, b0h, b0l, k0 + 64)
        G3_COMPUTE()
        __syncthreads();
        G3_STORE(a1h, a1l, b1h, b1l)
        __syncthreads();
        if (k0 + 96 < K) G3_LOAD(a1h, a1l, b1h, b1l, k0 + 96)
        G3_COMPUTE()
        __syncthreads();
    }
#undef G3_LOAD
#undef G3_STORE
#undef G3_COMPUTE

#pragma unroll
    for (int mi = 0; mi < FM; ++mi) {
#pragma unroll
        for (int ni = 0; ni < FN; ++ni) {
            int col = n0 + wn * (TN / 2) + ni * 16 + l16;
#pragma unroll
            for (int r = 0; r < 4; ++r) {
                int row = wm * (TM / 2) + mi * 16 + quad * 4 + r;
                float v = acc[mi][ni][r];
                if (MODE == 0) {
                    C[(size_t)(m0 + row) * N + col] = v;
                } else if (MODE == 1) {
                    C[(size_t)(m0 + row) * N + col] += v;
                } else {  // MODE 5
                    int rr = m0 + row;
                    if (rr < count) {
                        int dest = tok[offs + rr];
                        float w = twt[offs + rr];
                        atomicAdd(&C[(size_t)dest * N + col], w * v);
                    }
                }
            }
        }
    }
}

// ---------------------------------------------------------------------------
// Fused FFN up on pre-split operands: t = silu(A@W1^T) * (A@W3^T).
// Emits t PRE-SPLIT (hi/lo).  TM=64 x TN=128, register prefetch.
// GATHER: rows via tok[] (MoE, blockIdx.z=expert, compact output rows).
// ---------------------------------------------------------------------------
template<bool GATHER>
__global__ __launch_bounds__(256) void ffn_fusedp(
    const unsigned short* __restrict__ Ahi, const unsigned short* __restrict__ Alo,
    const unsigned short* __restrict__ W1hibase, const unsigned short* __restrict__ W1lobase,
    const unsigned short* __restrict__ W3hibase, const unsigned short* __restrict__ W3lobase,
    unsigned short* __restrict__ Thi, unsigned short* __restrict__ Tlo,
    int M, int N, int K,
    const int* __restrict__ tok, const int* __restrict__ counts,
    const int* __restrict__ offsets, size_t wstride)
{
    constexpr int TM = 64, TN = 128, PAD = 40;
    constexpr int FM = 2, FN = 4;

    int e = GATHER ? blockIdx.z : 0;
    int count = M, offs = 0;
    if (GATHER) {
        count = counts[e];
        offs  = offsets[e];
        if ((int)(blockIdx.y * TM) >= count) return;
    }
    const unsigned short* W1hi = W1hibase + (size_t)e * wstride;
    const unsigned short* W1lo = W1lobase + (size_t)e * wstride;
    const unsigned short* W3hi = W3hibase + (size_t)e * wstride;
    const unsigned short* W3lo = W3lobase + (size_t)e * wstride;

    __shared__ __align__(16) unsigned short Ah[TM][PAD];
    __shared__ __align__(16) unsigned short Al[TM][PAD];
    __shared__ __align__(16) unsigned short B1h[TN][PAD];
    __shared__ __align__(16) unsigned short B1l[TN][PAD];
    __shared__ __align__(16) unsigned short B3h[TN][PAD];
    __shared__ __align__(16) unsigned short B3l[TN][PAD];
    __shared__ int sTok[TM];

    int tid = threadIdx.x;
    int m0 = blockIdx.y * TM, n0 = blockIdx.x * TN;

    if (GATHER) {
        if (tid < TM) {
            int r = m0 + tid;
            sTok[tid] = (r < count) ? tok[offs + r] : tok[offs];
        }
        __syncthreads();
    }

    int srow = tid >> 2;
    int scol = (tid & 3) * 8;
    int wave = tid >> 6, lane = tid & 63;
    int wm = wave >> 1, wn = wave & 1;
    int quad = lane >> 4, l16 = lane & 15;

    f32x4 accg[FM][FN], accu[FM][FN];
#pragma unroll
    for (int mi = 0; mi < FM; ++mi)
#pragma unroll
        for (int ni = 0; ni < FN; ++ni) {
            accg[mi][ni] = (f32x4){0.f, 0.f, 0.f, 0.f};
            accu[mi][ni] = (f32x4){0.f, 0.f, 0.f, 0.f};
        }

    size_t arow;
    if (GATHER) arow = (size_t)sTok[srow] * K;
    else        arow = (size_t)(m0 + srow) * K;
    size_t brow[2];
    brow[0] = (size_t)(n0 + srow) * K;
    brow[1] = (size_t)(n0 + 64 + srow) * K;

    ushort8v pah, pal, p1h[2], p1l[2], p3h[2], p3l[2];
    pah = *(const ushort8v*)(Ahi + arow + scol);
    pal = *(const ushort8v*)(Alo + arow + scol);
#pragma unroll
    for (int p = 0; p < 2; ++p) {
        p1h[p] = *(const ushort8v*)(W1hi + brow[p] + scol);
        p1l[p] = *(const ushort8v*)(W1lo + brow[p] + scol);
        p3h[p] = *(const ushort8v*)(W3hi + brow[p] + scol);
        p3l[p] = *(const ushort8v*)(W3lo + brow[p] + scol);
    }

    for (int k0 = 0; k0 < K; k0 += 32) {
        *(ushort8v*)&Ah[srow][scol] = pah;
        *(ushort8v*)&Al[srow][scol] = pal;
#pragma unroll
        for (int p = 0; p < 2; ++p) {
            int row = p * 64 + srow;
            *(ushort8v*)&B1h[row][scol] = p1h[p];
            *(ushort8v*)&B1l[row][scol] = p1l[p];
            *(ushort8v*)&B3h[row][scol] = p3h[p];
            *(ushort8v*)&B3l[row][scol] = p3l[p];
        }
        __syncthreads();
        if (k0 + 32 < K) {
            int kn = k0 + 32;
            pah = *(const ushort8v*)(Ahi + arow + kn + scol);
            pal = *(const ushort8v*)(Alo + arow + kn + scol);
#pragma unroll
            for (int p = 0; p < 2; ++p) {
                p1h[p] = *(const ushort8v*)(W1hi + brow[p] + kn + scol);
                p1l[p] = *(const ushort8v*)(W1lo + brow[p] + kn + scol);
                p3h[p] = *(const ushort8v*)(W3hi + brow[p] + kn + scol);
                p3l[p] = *(const ushort8v*)(W3lo + brow[p] + kn + scol);
            }
        }

        bf16x8 ah[FM], al[FM], bh[FN], bl[FN];
#pragma unroll
        for (int mi = 0; mi < FM; ++mi) {
            ah[mi] = *(const bf16x8*)&Ah[wm * 32 + mi * 16 + l16][quad * 8];
            al[mi] = *(const bf16x8*)&Al[wm * 32 + mi * 16 + l16][quad * 8];
        }
        // gate = A @ W1^T
#pragma unroll
        for (int ni = 0; ni < FN; ++ni) {
            bh[ni] = *(const bf16x8*)&B1h[wn * 64 + ni * 16 + l16][quad * 8];
            bl[ni] = *(const bf16x8*)&B1l[wn * 64 + ni * 16 + l16][quad * 8];
        }
#pragma unroll
        for (int mi = 0; mi < FM; ++mi)
#pragma unroll
            for (int ni = 0; ni < FN; ++ni) {
                accg[mi][ni] = __builtin_amdgcn_mfma_f32_16x16x32_bf16(
                    ah[mi], bh[ni], accg[mi][ni], 0, 0, 0);
                accg[mi][ni] = __builtin_amdgcn_mfma_f32_16x16x32_bf16(
                    al[mi], bh[ni], accg[mi][ni], 0, 0, 0);
                accg[mi][ni] = __builtin_amdgcn_mfma_f32_16x16x32_bf16(
                    ah[mi], bl[ni], accg[mi][ni], 0, 0, 0);
            }
        // up = A @ W3^T
#pragma unroll
        for (int ni = 0; ni < FN; ++ni) {
            bh[ni] = *(const bf16x8*)&B3h[wn * 64 + ni * 16 + l16][quad * 8];
            bl[ni] = *(const bf16x8*)&B3l[wn * 64 + ni * 16 + l16][quad * 8];
        }
#pragma unroll
        for (int mi = 0; mi < FM; ++mi)
#pragma unroll
            for (int ni = 0; ni < FN; ++ni) {
                accu[mi][ni] = __builtin_amdgcn_mfma_f32_16x16x32_bf16(
                    ah[mi], bh[ni], accu[mi][ni], 0, 0, 0);
                accu[mi][ni] = __builtin_amdgcn_mfma_f32_16x16x32_bf16(
                    al[mi], bh[ni], accu[mi][ni], 0, 0, 0);
                accu[mi][ni] = __builtin_amdgcn_mfma_f32_16x16x32_bf16(
                    ah[mi], bl[ni], accu[mi][ni], 0, 0, 0);
            }
        __syncthreads();
    }

#pragma unroll
    for (int mi = 0; mi < FM; ++mi) {
#pragma unroll
        for (int ni = 0; ni < FN; ++ni) {
            int col = n0 + wn * 64 + ni * 16 + l16;
#pragma unroll
            for (int r = 0; r < 4; ++r) {
                int row = wm * 32 + mi * 16 + quad * 4 + r;
                float g = accg[mi][ni][r];
                float u = accu[mi][ni][r];
                float t = (g / (1.0f + expf(-g))) * u;
                unsigned short th, tl;
                splitbf(t, th, tl);
                if (GATHER) {
                    int rr = m0 + row;
                    if (rr < count) {
                        size_t idx = (size_t)(offs + rr) * N + col;
                        Thi[idx] = th; Tlo[idx] = tl;
                    }
                } else {
                    size_t idx = (size_t)(m0 + row) * N + col;
                    Thi[idx] = th; Tlo[idx] = tl;
                }
            }
        }
    }
}

// ---------------------------------------------------------------------------
// RoPE in-place over q,k slices of qkv [N, 3*D]
// ---------------------------------------------------------------------------
__global__ __launch_bounds__(256) void rope_kernel(float* __restrict__ qkv)
{
    const int HD2 = HDc / 2;
    int idx = blockIdx.x * blockDim.x + threadIdx.x;
    int total = Nc * NHc * HD2;
    if (idx >= total) return;
    int i = idx % HD2;
    int hh = (idx / HD2) % NHc;
    int n = idx / (HD2 * NHc);
    int t = n % Tc;
    float invf = expf(-(2.0f * (float)i / (float)HDc) * logf(10000.0f));
    float f = (float)t * invf;
    float c = cosf(f), s = sinf(f);
    size_t base = (size_t)n * (3 * Dc) + (size_t)hh * HDc;
    float* qp = qkv + base;
    float* kp = qkv + base + Dc;
    float q1 = qp[i], q2 = qp[i + HD2];
    qp[i]       = q1 * c - q2 * s;
    qp[i + HD2] = q1 * s + q2 * c;
    float k1 = kp[i], k2 = kp[i + HD2];
    kp[i]       = k1 * c - k2 * s;
    kp[i + HD2] = k1 * s + k2 * c;
}

// ---------------------------------------------------------------------------
// MFMA flash attention, bf16x3 precision.  Emits output PRE-SPLIT (hi/lo)
// for the out-projection GEMM.
// ---------------------------------------------------------------------------
__global__ __launch_bounds__(256) void attn_mfma(
    const float* __restrict__ qkv, unsigned short* __restrict__ outh,
    unsigned short* __restrict__ outl)
{
    constexpr int PAD = 72;
    __shared__ __align__(16) unsigned short Qh[64][PAD];
    __shared__ __align__(16) unsigned short Ql[64][PAD];
    __shared__ __align__(16) unsigned short Kh[64][PAD];   // aliased: P-hi
    __shared__ __align__(16) unsigned short Kl[64][PAD];   // aliased: P-lo
    __shared__ __align__(16) unsigned short Vth[64][PAD];  // V^T [hd][kv]
    __shared__ __align__(16) unsigned short Vtl[64][PAD];

    int qb = blockIdx.x, bh = blockIdx.y;
    int b = bh >> 3, hh = bh & 7;
    const int D3 = 3 * Dc;
    const float* base = qkv + (size_t)b * Tc * D3 + (size_t)hh * HDc;

    int tid = threadIdx.x;
    int wave = tid >> 6, lane = tid & 63;
    int quad = lane >> 4, l16 = lane & 15;

    int srow = tid >> 2;
    int scb  = (tid & 3) * 16;
    int vhd  = lane;
    int vkb  = wave * 16;

    {
        const float* qp = base + (size_t)(qb * 64 + srow) * D3 + scb;
        float4 q0 = *(const float4*)(qp);
        float4 q1 = *(const float4*)(qp + 4);
        float4 q2 = *(const float4*)(qp + 8);
        float4 q3 = *(const float4*)(qp + 12);
        const float sc = 0.125f;
        q0.x *= sc; q0.y *= sc; q0.z *= sc; q0.w *= sc;
        q1.x *= sc; q1.y *= sc; q1.z *= sc; q1.w *= sc;
        q2.x *= sc; q2.y *= sc; q2.z *= sc; q2.w *= sc;
        q3.x *= sc; q3.y *= sc; q3.z *= sc; q3.w *= sc;
        ushort8v h, l;
        split8(q0, q1, h, l);
        *(ushort8v*)&Qh[srow][scb]     = h;
        *(ushort8v*)&Ql[srow][scb]     = l;
        split8(q2, q3, h, l);
        *(ushort8v*)&Qh[srow][scb + 8] = h;
        *(ushort8v*)&Ql[srow][scb + 8] = l;
    }
    __syncthreads();
    bf16x8 qah[2], qal[2];
#pragma unroll
    for (int ks = 0; ks < 2; ++ks) {
        qah[ks] = *(const bf16x8*)&Qh[wave * 16 + l16][ks * 32 + quad * 8];
        qal[ks] = *(const bf16x8*)&Ql[wave * 16 + l16][ks * 32 + quad * 8];
    }

    float4 kf0, kf1, kf2, kf3;
    float vf[16];
    {
        const float* kp = base + (size_t)srow * D3 + Dc + scb;
        kf0 = *(const float4*)(kp);
        kf1 = *(const float4*)(kp + 4);
        kf2 = *(const float4*)(kp + 8);
        kf3 = *(const float4*)(kp + 12);
        const float* vp = base + (size_t)vkb * D3 + 2 * Dc + vhd;
#pragma unroll
        for (int i = 0; i < 16; ++i) vf[i] = vp[(size_t)i * D3];
    }

    f32x4 o[4];
#pragma unroll
    for (int f = 0; f < 4; ++f) o[f] = (f32x4){0.f, 0.f, 0.f, 0.f};
    float mrow[4], lrow[4];
#pragma unroll
    for (int r = 0; r < 4; ++r) { mrow[r] = -1e30f; lrow[r] = 0.0f; }

    for (int kt = 0; kt <= qb; ++kt) {
        __syncthreads();
        {
            ushort8v h, l;
            split8(kf0, kf1, h, l);
            *(ushort8v*)&Kh[srow][scb]     = h;
            *(ushort8v*)&Kl[srow][scb]     = l;
            split8(kf2, kf3, h, l);
            *(ushort8v*)&Kh[srow][scb + 8] = h;
            *(ushort8v*)&Kl[srow][scb + 8] = l;
        }
        {
            float4 v0 = make_float4(vf[0], vf[1], vf[2], vf[3]);
            float4 v1 = make_float4(vf[4], vf[5], vf[6], vf[7]);
            float4 v2 = make_float4(vf[8], vf[9], vf[10], vf[11]);
            float4 v3 = make_float4(vf[12], vf[13], vf[14], vf[15]);
            ushort8v h, l;
            split8(v0, v1, h, l);
            *(ushort8v*)&Vth[vhd][vkb]     = h;
            *(ushort8v*)&Vtl[vhd][vkb]     = l;
            split8(v2, v3, h, l);
            *(ushort8v*)&Vth[vhd][vkb + 8] = h;
            *(ushort8v*)&Vtl[vhd][vkb + 8] = l;
        }
        __syncthreads();
        if (kt < qb) {
            const float* kp = base + (size_t)((kt + 1) * 64 + srow) * D3 + Dc + scb;
            kf0 = *(const float4*)(kp);
            kf1 = *(const float4*)(kp + 4);
            kf2 = *(const float4*)(kp + 8);
            kf3 = *(const float4*)(kp + 12);
            const float* vp = base + (size_t)((kt + 1) * 64 + vkb) * D3 + 2 * Dc + vhd;
#pragma unroll
            for (int i = 0; i < 16; ++i) vf[i] = vp[(size_t)i * D3];
        }

        f32x4 s[4];
#pragma unroll
        for (int ni = 0; ni < 4; ++ni) s[ni] = (f32x4){0.f, 0.f, 0.f, 0.f};
#pragma unroll
        for (int ks = 0; ks < 2; ++ks) {
            bf16x8 kh_[4], kl_[4];
#pragma unroll
            for (int ni = 0; ni < 4; ++ni) {
                kh_[ni] = *(const bf16x8*)&Kh[ni * 16 + l16][ks * 32 + quad * 8];
                kl_[ni] = *(const bf16x8*)&Kl[ni * 16 + l16][ks * 32 + quad * 8];
            }
#pragma unroll
            for (int ni = 0; ni < 4; ++ni) {
                s[ni] = __builtin_amdgcn_mfma_f32_16x16x32_bf16(
                    qah[ks], kh_[ni], s[ni], 0, 0, 0);
                s[ni] = __builtin_amdgcn_mfma_f32_16x16x32_bf16(
                    qal[ks], kh_[ni], s[ni], 0, 0, 0);
                s[ni] = __builtin_amdgcn_mfma_f32_16x16x32_bf16(
                    qah[ks], kl_[ni], s[ni], 0, 0, 0);
            }
        }

        if (kt == qb) {
#pragma unroll
            for (int ni = 0; ni < 4; ++ni)
#pragma unroll
                for (int r = 0; r < 4; ++r)
                    if (ni * 16 + l16 > wave * 16 + quad * 4 + r)
                        s[ni][r] = -1e30f;
        }

        float al4[4];
#pragma unroll
        for (int r = 0; r < 4; ++r) {
            float rm = fmaxf(fmaxf(s[0][r], s[1][r]), fmaxf(s[2][r], s[3][r]));
            rm = fmaxf(rm, __shfl_xor(rm, 1));
            rm = fmaxf(rm, __shfl_xor(rm, 2));
            rm = fmaxf(rm, __shfl_xor(rm, 4));
            rm = fmaxf(rm, __shfl_xor(rm, 8));
            float mn = fmaxf(mrow[r], rm);
            al4[r] = __expf(mrow[r] - mn);
            mrow[r] = mn;
            float rs = 0.0f;
#pragma unroll
            for (int ni = 0; ni < 4; ++ni) {
                float pv = __expf(s[ni][r] - mn);
                s[ni][r] = pv;
                rs += pv;
            }
            rs += __shfl_xor(rs, 1);
            rs += __shfl_xor(rs, 2);
            rs += __shfl_xor(rs, 4);
            rs += __shfl_xor(rs, 8);
            lrow[r] = lrow[r] * al4[r] + rs;
        }

        __syncthreads();
#pragma unroll
        for (int ni = 0; ni < 4; ++ni)
#pragma unroll
            for (int r = 0; r < 4; ++r) {
                unsigned short hp, lp;
                splitbf(s[ni][r], hp, lp);
                Kh[wave * 16 + quad * 4 + r][ni * 16 + l16] = hp;
                Kl[wave * 16 + quad * 4 + r][ni * 16 + l16] = lp;
            }
#pragma unroll
        for (int f = 0; f < 4; ++f)
#pragma unroll
            for (int r = 0; r < 4; ++r)
                o[f][r] *= al4[r];
#pragma unroll
        for (int ks = 0; ks < 2; ++ks) {
            bf16x8 pah = *(const bf16x8*)&Kh[wave * 16 + l16][ks * 32 + quad * 8];
            bf16x8 pal = *(const bf16x8*)&Kl[wave * 16 + l16][ks * 32 + quad * 8];
#pragma unroll
            for (int f = 0; f < 4; ++f) {
                bf16x8 vh_ = *(const bf16x8*)&Vth[f * 16 + l16][ks * 32 + quad * 8];
                bf16x8 vl_ = *(const bf16x8*)&Vtl[f * 16 + l16][ks * 32 + quad * 8];
                o[f] = __builtin_amdgcn_mfma_f32_16x16x32_bf16(
                    pah, vh_, o[f], 0, 0, 0);
                o[f] = __builtin_amdgcn_mfma_f32_16x16x32_bf16(
                    pal, vh_, o[f], 0, 0, 0);
                o[f] = __builtin_amdgcn_mfma_f32_16x16x32_bf16(
                    pah, vl_, o[f], 0, 0, 0);
            }
        }
    }

#pragma unroll
    for (int r = 0; r < 4; ++r) {
        float inv = 1.0f / lrow[r];
        int q = qb * 64 + wave * 16 + quad * 4 + r;
#pragma unroll
        for (int f = 0; f < 4; ++f) {
            size_t idx = (size_t)(b * Tc + q) * Dc + hh * HDc + f * 16 + l16;
            unsigned short hp, lp;
            splitbf(o[f][r] * inv, hp, lp);
            outh[idx] = hp; outl[idx] = lp;
        }
    }
}

// ---------------------------------------------------------------------------
// Router logits: one wave per token
// ---------------------------------------------------------------------------
__global__ __launch_bounds__(64) void router_kernel(
    const float* __restrict__ x, const float* __restrict__ rw,
    float* __restrict__ logits)
{
    int n = blockIdx.x;
    int lane = threadIdx.x;
    const float* xr = x + (size_t)n * Dc;
    for (int e = 0; e < Ec; ++e) {
        const float* wr = rw + (size_t)e * Dc;
        float p = 0.0f;
        for (int d = lane; d < Dc; d += 64) p += xr[d] * wr[d];
        for (int off = 32; off > 0; off >>= 1) p += __shfl_down(p, off);
        if (lane == 0) logits[(size_t)n * Ec + e] = p;
    }
}

__global__ void zero8_kernel(int* __restrict__ counts)
{
    if (threadIdx.x < Ec) counts[threadIdx.x] = 0;
}

__global__ __launch_bounds__(256) void topk_count_kernel(
    const float* __restrict__ logits, int* __restrict__ counts,
    int2* __restrict__ eidx, float2* __restrict__ ewt)
{
    int n = blockIdx.x * blockDim.x + threadIdx.x;
    if (n >= Nc) return;
    const float* lg = logits + (size_t)n * Ec;
    int i0 = -1, i1 = -1;
    float v0 = -1e30f, v1 = -1e30f;
    for (int e = 0; e < Ec; ++e) {
        float v = lg[e];
        if (v > v0) { v1 = v0; i1 = i0; v0 = v; i0 = e; }
        else if (v > v1) { v1 = v; i1 = e; }
    }
    float e1 = expf(v1 - v0);
    float w0 = 1.0f / (1.0f + e1);
    float w1 = e1 / (1.0f + e1);
    atomicAdd(&counts[i0], 1);
    atomicAdd(&counts[i1], 1);
    eidx[n] = make_int2(i0, i1);
    ewt[n]  = make_float2(w0, w1);
}

__global__ void scan_kernel(int* __restrict__ counts, int* __restrict__ offsets)
{
    if (threadIdx.x == 0) {
        int s = 0;
        for (int e = 0; e < Ec; ++e) { offsets[e] = s; s += counts[e]; counts[e] = 0; }
    }
}

__global__ __launch_bounds__(256) void topk_place_kernel(
    const int2* __restrict__ eidx, const float2* __restrict__ ewt,
    int* __restrict__ counts, const int* __restrict__ offsets,
    int* __restrict__ tok, float* __restrict__ twt)
{
    int n = blockIdx.x * blockDim.x + threadIdx.x;
    if (n >= Nc) return;
    int2 ei = eidx[n];
    float2 w = ewt[n];
    int p0 = atomicAdd(&counts[ei.x], 1);
    int r0 = offsets[ei.x] + p0;
    tok[r0] = n; twt[r0] = w.x;
    int p1 = atomicAdd(&counts[ei.y], 1);
    int r1 = offsets[ei.y] + p1;
    tok[r1] = n; twt[r1] = w.y;
}

// ---------------------------------------------------------------------------
// Host-side orchestration
// ---------------------------------------------------------------------------
extern "C" void kernel_launch(void* const* d_in, const int* in_sizes, int n_in,
                              void* d_out, int out_size, void* d_ws, size_t ws_size,
                              hipStream_t stream)
{
    const float* x        = (const float*)d_in[0];
    const float* qkv_w    = (const float*)d_in[1];
    const float* out_w    = (const float*)d_in[2];
    const float* norm1_w  = (const float*)d_in[3];
    const float* norm2_w  = (const float*)d_in[4];
    const float* router_w = (const float*)d_in[5];
    const float* moe_w1   = (const float*)d_in[6];
    const float* moe_w2   = (const float*)d_in[7];
    const float* moe_w3   = (const float*)d_in[8];
    const float* f_w1     = (const float*)d_in[9];
    const float* f_w2     = (const float*)d_in[10];
    const float* f_w3     = (const float*)d_in[11];
    const float* norm_f   = (const float*)d_in[12];
    float* out = (float*)d_out;

    // workspace (~118 MB)
    float* p = (float*)d_ws;
    float* h      = p;  p += Nc * Dc;
    float* xn     = p;  p += Nc * Dc;
    unsigned short* xnh = (unsigned short*)p;  p += Nc * Dc / 2;
    unsigned short* xnl = (unsigned short*)p;  p += Nc * Dc / 2;
    float* arena  = p;  p += (size_t)NKc * Hc;   // qkv fp32 OR t hi+lo
    float* logits = p;  p += Nc * Ec;
    int*   counts  = (int*)p;  p += 16;
    int*   offsets = (int*)p;  p += 16;
    int2*  eidx    = (int2*)p; p += 2 * Nc;
    float* ewt     = p;        p += 2 * Nc;
    int*   tok     = (int*)p;  p += NKc;
    float* twt     = p;        p += NKc;
    // pre-split weight buffers (ushort counts)
    unsigned short* wqh = (unsigned short*)p;
    unsigned short* wql = wqh + (size_t)3 * Dc * Dc;
    unsigned short* woh = wql + (size_t)3 * Dc * Dc;
    unsigned short* wol = woh + (size_t)Dc * Dc;
    unsigned short* wah = wol + (size_t)Dc * Dc;          // w1 / later w2
    unsigned short* wal = wah + (size_t)Ec * Hc * Dc;
    unsigned short* wbh = wal + (size_t)Ec * Hc * Dc;     // w3
    unsigned short* wbl = wbh + (size_t)Ec * Hc * Dc;

    float* qkv = arena;                         // [Nc][3*Dc] fp32, attn phase
    unsigned short* th = (unsigned short*)arena;         // t hi, FFN phase
    unsigned short* tl = th + (size_t)NKc * Hc;          // t lo

    hipMemcpyAsync(h, x, (size_t)Nc * Dc * sizeof(float),
                   hipMemcpyDeviceToDevice, stream);

    for (int l = 0; l < Lc; ++l) {
        // --- attention block ---
        {
            int n4 = 3 * Dc * Dc / 4;
            split_w_kernel<<<(n4 + 255) / 256, 256, 0, stream>>>(
                qkv_w + (size_t)l * 3 * Dc * Dc, wqh, wql, n4);
        }
        rmsnorm_split_kernel<<<Nc, 256, 0, stream>>>(
            h, norm1_w + (size_t)l * Dc, xn, xnh, xnl);
        gemm3p<0, 64, 128><<<dim3(3 * Dc / 128, Nc / 64, 1), 256, 0, stream>>>(
            xnh, xnl, wqh, wql, qkv, Nc, 3 * Dc, Dc,
            nullptr, nullptr, nullptr, nullptr, 0);
        {
            int total = Nc * NHc * (HDc / 2);
            rope_kernel<<<(total + 255) / 256, 256, 0, stream>>>(qkv);
        }
        {
            int n4 = Dc * Dc / 4;
            split_w_kernel<<<(n4 + 255) / 256, 256, 0, stream>>>(
                out_w + (size_t)l * Dc * Dc, woh, wol, n4);
        }
        attn_mfma<<<dim3(Tc / 64, Bc * NHc), 256, 0, stream>>>(qkv, xnh, xnl);
        gemm3p<1, 64, 64><<<dim3(Dc / 64, Nc / 64, 1), 256, 0, stream>>>(
            xnh, xnl, woh, wol, h, Nc, Dc, Dc,
            nullptr, nullptr, nullptr, nullptr, 0);

        // --- FFN block ---
        rmsnorm_split_kernel<<<Nc, 256, 0, stream>>>(
            h, norm2_w + (size_t)l * Dc, xn, xnh, xnl);
        if (l == 0 || l == 2) {
            int m = l / 2;
            router_kernel<<<Nc, 64, 0, stream>>>(
                xn, router_w + (size_t)m * Ec * Dc, logits);
            zero8_kernel<<<1, 64, 0, stream>>>(counts);
            topk_count_kernel<<<Nc / 256, 256, 0, stream>>>(
                logits, counts, eidx, (float2*)ewt);
            scan_kernel<<<1, 64, 0, stream>>>(counts, offsets);
            topk_place_kernel<<<Nc / 256, 256, 0, stream>>>(
                eidx, (float2*)ewt, counts, offsets, tok, twt);

            int n4 = Ec * Hc * Dc / 4;
            split_w_kernel<<<(n4 + 255) / 256, 256, 0, stream>>>(
                moe_w1 + (size_t)m * Ec * Hc * Dc, wah, wal, n4);
            split_w_kernel<<<(n4 + 255) / 256, 256, 0, stream>>>(
                moe_w3 + (size_t)m * Ec * Hc * Dc, wbh, wbl, n4);
            ffn_fusedp<true><<<dim3(Hc / 128, NKc / 64, Ec), 256, 0, stream>>>(
                xnh, xnl, wah, wal, wbh, wbl, th, tl, Nc, Hc, Dc,
                tok, counts, offsets, (size_t)Hc * Dc);
            split_w_kernel<<<(n4 + 255) / 256, 256, 0, stream>>>(
                moe_w2 + (size_t)m * Ec * Dc * Hc, wah, wal, n4);
            gemm3p<5, 64, 128><<<dim3(Dc / 128, NKc / 64, Ec), 256, 0, stream>>>(
                th, tl, wah, wal, h, Nc, Dc, Hc,
                tok, twt, counts, offsets, (size_t)Dc * Hc);
        } else {
            int m = (l - 1) / 2;
            int n4 = Hc * Dc / 4;
            split_w_kernel<<<(n4 + 255) / 256, 256, 0, stream>>>(
                f_w1 + (size_t)m * Hc * Dc, wah, wal, n4);
            split_w_kernel<<<(n4 + 255) / 256, 256, 0, stream>>>(
                f_w3 + (size_t)m * Hc * Dc, wbh, wbl, n4);
            ffn_fusedp<false><<<dim3(Hc / 128, Nc / 64, 1), 256, 0, stream>>>(
                xnh, xnl, wah, wal, wbh, wbl, th, tl, Nc, Hc, Dc,
                nullptr, nullptr, nullptr, 0);
            split_w_kernel<<<(n4 + 255) / 256, 256, 0, stream>>>(
                f_w2 + (size_t)m * Dc * Hc, wah, wal, n4);
            gemm3p<1, 64, 128><<<dim3(Dc / 128, Nc / 64, 1), 256, 0, stream>>>(
                th, tl, wah, wal, h, Nc, Dc, Hc,
                nullptr, nullptr, nullptr, nullptr, 0);
        }
    }

    rmsnorm_kernel<<<Nc, 256, 0, stream>>>(h, norm_f, out);
}

// Round 6
// 1244.425 us; speedup vs baseline: 2.0188x; 1.0513x over previous
//
#include <hip/hip_runtime.h>
#include <hip/hip_bf16.h>
#include <math.h>

// Problem constants
#define Bc 2
#define Tc 1024
#define Dc 512
#define NHc 8
#define Lc 4
#define Ec 8
#define Kc 2
#define Hc 2048
#define HDc 64
#define Nc (Bc * Tc)   // 2048 tokens
#define NKc (Nc * Kc)  // 4096 compact MoE rows

typedef __bf16 bf16x8 __attribute__((ext_vector_type(8)));
typedef float  f32x4  __attribute__((ext_vector_type(4)));
typedef unsigned short ushort8v __attribute__((ext_vector_type(8)));
typedef unsigned short ushort4v __attribute__((ext_vector_type(4)));

__device__ inline unsigned short f2bf(float f) {
    union { float f; unsigned u; } v; v.f = f;
    unsigned r = v.u + 0x7FFFu + ((v.u >> 16) & 1u);   // RNE
    return (unsigned short)(r >> 16);
}
__device__ inline float bf2f(unsigned short b) {
    union { unsigned u; float f; } v; v.u = ((unsigned)b) << 16;
    return v.f;
}
// split a = hi + lo (each bf16); residual ~2^-17 relative
__device__ inline void splitbf(float a, unsigned short& hi, unsigned short& lo) {
    unsigned short h = f2bf(a);
    hi = h;
    lo = f2bf(a - bf2f(h));
}

// ---------------------------------------------------------------------------
// Weight pre-split: fp32 -> (hi, lo) bf16 ushort arrays.
// ---------------------------------------------------------------------------
__global__ __launch_bounds__(256) void split_w_kernel(
    const float* __restrict__ w, unsigned short* __restrict__ hi,
    unsigned short* __restrict__ lo, int n4)
{
    int i = blockIdx.x * 256 + threadIdx.x;
    if (i >= n4) return;
    float4 v = ((const float4*)w)[i];
    ushort4v h, l;
    unsigned short a, b;
    splitbf(v.x, a, b); h[0] = a; l[0] = b;
    splitbf(v.y, a, b); h[1] = a; l[1] = b;
    splitbf(v.z, a, b); h[2] = a; l[2] = b;
    splitbf(v.w, a, b); h[3] = a; l[3] = b;
    ((ushort4v*)hi)[i] = h;
    ((ushort4v*)lo)[i] = l;
}

// ---------------------------------------------------------------------------
// RMSNorm emitting fp32 (for router) + pre-split hi/lo (for GEMM A-operand)
// ---------------------------------------------------------------------------
__global__ __launch_bounds__(256) void rmsnorm_split_kernel(
    const float* __restrict__ x, const float* __restrict__ w,
    float* __restrict__ y, unsigned short* __restrict__ yh,
    unsigned short* __restrict__ yl)
{
    int row = blockIdx.x;
    const float* xr = x + (size_t)row * Dc;
    __shared__ float red[256];
    int tid = threadIdx.x;
    float ss = 0.0f;
    for (int d = tid; d < Dc; d += 256) { float v = xr[d]; ss += v * v; }
    red[tid] = ss; __syncthreads();
    for (int s = 128; s > 0; s >>= 1) {
        if (tid < s) red[tid] += red[tid + s];
        __syncthreads();
    }
    float inv = rsqrtf(red[0] / (float)Dc + 1e-5f);
    for (int d = tid; d < Dc; d += 256) {
        float v = w[d] * xr[d] * inv;
        size_t idx = (size_t)row * Dc + d;
        y[idx] = v;
        unsigned short h, l;
        splitbf(v, h, l);
        yh[idx] = h; yl[idx] = l;
    }
}

// plain fp32 rmsnorm (final output)
__global__ __launch_bounds__(256) void rmsnorm_kernel(
    const float* __restrict__ x, const float* __restrict__ w,
    float* __restrict__ y)
{
    int row = blockIdx.x;
    const float* xr = x + (size_t)row * Dc;
    __shared__ float red[256];
    int tid = threadIdx.x;
    float ss = 0.0f;
    for (int d = tid; d < Dc; d += 256) { float v = xr[d]; ss += v * v; }
    red[tid] = ss; __syncthreads();
    for (int s = 128; s > 0; s >>= 1) {
        if (tid < s) red[tid] += red[tid + s];
        __syncthreads();
    }
    float inv = rsqrtf(red[0] / (float)Dc + 1e-5f);
    for (int d = tid; d < Dc; d += 256)
        y[(size_t)row * Dc + d] = w[d] * xr[d] * inv;
}

// ---------------------------------------------------------------------------
// bf16x3 MFMA GEMM on PRE-SPLIT operands: C[M,N] (op)= A @ W^T.
// BK=32, 4 waves (2x2), prefetch depth 2 (two named register sets, K-loop
// unrolled x2), pad-40 LDS.  Requires (K/KSPLIT) % 64 == 0.
// KSPLIT>1: K split across blockIdx.z slices; partial sums combined with
// device atomics (MODE 2/5).
// MODE 0: C =    MODE 1: C +=    MODE 2: atomicAdd(C, v)  [split-K accum]
// MODE 5: A rows compact [offs..offs+count) (MoE t), W per expert
//         (blockIdx.z/KSPLIT), scatter atomicAdd C[tok[r]] += twt[r]*v
// NOTE: no XCD swizzle — with MoE early-return it concentrates all active
// tiles onto one XCD (r3 post-mortem: 4x regression).
// ---------------------------------------------------------------------------
template<int MODE, int TM, int TN, int KSPLIT>
__global__ __launch_bounds__(256) void gemm3p(
    const unsigned short* __restrict__ Ahi, const unsigned short* __restrict__ Alo,
    const unsigned short* __restrict__ Whibase, const unsigned short* __restrict__ Wlobase,
    float* __restrict__ C, int M, int N, int K,
    const int* __restrict__ tok, const float* __restrict__ twt,
    const int* __restrict__ counts, const int* __restrict__ offsets,
    size_t wstride)
{
    constexpr int PAD = 40;
    constexpr int PA  = TM / 64;
    constexpr int PB  = TN / 64;
    constexpr int FM  = TM / 32;
    constexpr int FN  = TN / 32;

    int zz = blockIdx.z;
    int e  = (MODE == 5) ? zz / KSPLIT : 0;
    int kz = (MODE == 5) ? zz % KSPLIT : zz;
    int count = M, offs = 0;
    if (MODE == 5) {
        count = counts[e];
        offs  = offsets[e];
        if ((int)(blockIdx.y * TM) >= count) return;
    }
    const unsigned short* Whi = Whibase + (size_t)e * wstride;
    const unsigned short* Wlo = Wlobase + (size_t)e * wstride;

    int Ksub = K / KSPLIT;
    int kbeg = kz * Ksub;

    __shared__ __align__(16) unsigned short Ah[TM][PAD];
    __shared__ __align__(16) unsigned short Al[TM][PAD];
    __shared__ __align__(16) unsigned short Bh[TN][PAD];
    __shared__ __align__(16) unsigned short Bl[TN][PAD];

    int tid = threadIdx.x;
    int m0 = blockIdx.y * TM, n0 = blockIdx.x * TN;
    int srow = tid >> 2;          // 0..63
    int scol = (tid & 3) * 8;     // 8 elems/thread

    int wave = tid >> 6, lane = tid & 63;
    int wm = wave >> 1, wn = wave & 1;
    int quad = lane >> 4, l16 = lane & 15;

    f32x4 acc[FM][FN];
#pragma unroll
    for (int mi = 0; mi < FM; ++mi)
#pragma unroll
        for (int ni = 0; ni < FN; ++ni)
            acc[mi][ni] = (f32x4){0.f, 0.f, 0.f, 0.f};

    size_t arow[PA];
#pragma unroll
    for (int p = 0; p < PA; ++p) {
        int row = p * 64 + srow;
        if (MODE == 5) {
            int rr = m0 + row; if (rr >= count) rr = 0;
            arow[p] = (size_t)(offs + rr) * K;
        } else {
            arow[p] = (size_t)(m0 + row) * K;
        }
    }
    size_t brow[PB];
#pragma unroll
    for (int p = 0; p < PB; ++p)
        brow[p] = (size_t)(n0 + p * 64 + srow) * K;

#define G3_LOAD(AH, AL, BH, BL, KN)                                       \
    {                                                                     \
        _Pragma("unroll")                                                 \
        for (int p = 0; p < PA; ++p) {                                    \
            AH[p] = *(const ushort8v*)(Ahi + arow[p] + (KN) + scol);      \
            AL[p] = *(const ushort8v*)(Alo + arow[p] + (KN) + scol);      \
        }                                                                 \
        _Pragma("unroll")                                                 \
        for (int p = 0; p < PB; ++p) {                                    \
            BH[p] = *(const ushort8v*)(Whi + brow[p] + (KN) + scol);      \
            BL[p] = *(const ushort8v*)(Wlo + brow[p] + (KN) + scol);      \
        }                                                                 \
    }

#define G3_STORE(AH, AL, BH, BL)                                          \
    {                                                                     \
        _Pragma("unroll")                                                 \
        for (int p = 0; p < PA; ++p) {                                    \
            *(ushort8v*)&Ah[p * 64 + srow][scol] = AH[p];                 \
            *(ushort8v*)&Al[p * 64 + srow][scol] = AL[p];                 \
        }                                                                 \
        _Pragma("unroll")                                                 \
        for (int p = 0; p < PB; ++p) {                                    \
            *(ushort8v*)&Bh[p * 64 + srow][scol] = BH[p];                 \
            *(ushort8v*)&Bl[p * 64 + srow][scol] = BL[p];                 \
        }                                                                 \
    }

#define G3_COMPUTE()                                                      \
    {                                                                     \
        bf16x8 ah[FM], al[FM], bh[FN], bl[FN];                            \
        _Pragma("unroll")                                                 \
        for (int mi = 0; mi < FM; ++mi) {                                 \
            ah[mi] = *(const bf16x8*)&Ah[wm * (TM / 2) + mi * 16 + l16][quad * 8]; \
            al[mi] = *(const bf16x8*)&Al[wm * (TM / 2) + mi * 16 + l16][quad * 8]; \
        }                                                                 \
        _Pragma("unroll")                                                 \
        for (int ni = 0; ni < FN; ++ni) {                                 \
            bh[ni] = *(const bf16x8*)&Bh[wn * (TN / 2) + ni * 16 + l16][quad * 8]; \
            bl[ni] = *(const bf16x8*)&Bl[wn * (TN / 2) + ni * 16 + l16][quad * 8]; \
        }                                                                 \
        _Pragma("unroll")                                                 \
        for (int mi = 0; mi < FM; ++mi)                                   \
            _Pragma("unroll")                                             \
            for (int ni = 0; ni < FN; ++ni) {                             \
                acc[mi][ni] = __builtin_amdgcn_mfma_f32_16x16x32_bf16(    \
                    ah[mi], bh[ni], acc[mi][ni], 0, 0, 0);                \
                acc[mi][ni] = __builtin_amdgcn_mfma_f32_16x16x32_bf16(    \
                    al[mi], bh[ni], acc[mi][ni], 0, 0, 0);                \
                acc[mi][ni] = __builtin_amdgcn_mfma_f32_16x16x32_bf16(    \
                    ah[mi], bl[ni], acc[mi][ni], 0, 0, 0);                \
            }                                                             \
    }

    // two named prefetch sets (static indexing; no scratch)
    ushort8v a0h[PA], a0l[PA], b0h[PB], b0l[PB];
    ushort8v a1h[PA], a1l[PA], b1h[PB], b1l[PB];
    G3_LOAD(a0h, a0l, b0h, b0l, kbeg)
    G3_LOAD(a1h, a1l, b1h, b1l, kbeg + 32)

    for (int k0 = kbeg; k0 < kbeg + Ksub; k0 += 64) {
        G3_STORE(a0h, a0l, b0h, b0l)
        __syncthreads();
        if (k0 + 64 < kbeg + Ksub) G3_LOAD(a0h, a0l, b0h, b0l, k0 + 64)
        G3_COMPUTE()
        __syncthreads();
        G3_STORE(a1h, a1l, b1h, b1l)
        __syncthreads();
        if (k0 + 96 < kbeg + Ksub) G3_LOAD(a1h, a1l, b1h, b1l, k0 + 96)
        G3_COMPUTE()
        __syncthreads();
    }
#undef G3_LOAD
#undef G3_STORE
#undef G3_COMPUTE

#pragma unroll
    for (int mi = 0; mi < FM; ++mi) {
#pragma unroll
        for (int ni = 0; ni < FN; ++ni) {
            int col = n0 + wn * (TN / 2) + ni * 16 + l16;
#pragma unroll
            for (int r = 0; r < 4; ++r) {
                int row = wm * (TM / 2) + mi * 16 + quad * 4 + r;
                float v = acc[mi][ni][r];
                if (MODE == 0) {
                    C[(size_t)(m0 + row) * N + col] = v;
                } else if (MODE == 1) {
                    C[(size_t)(m0 + row) * N + col] += v;
                } else if (MODE == 2) {
                    atomicAdd(&C[(size_t)(m0 + row) * N + col], v);
                } else {  // MODE 5
                    int rr = m0 + row;
                    if (rr < count) {
                        int dest = tok[offs + rr];
                        float w = twt[offs + rr];
                        atomicAdd(&C[(size_t)dest * N + col], w * v);
                    }
                }
            }
        }
    }
}

// ---------------------------------------------------------------------------
// Fused FFN up on pre-split operands: t = silu(A@W1^T) * (A@W3^T).
// Emits t PRE-SPLIT (hi/lo).  128x128 tile, 8 waves (512 thr), wave grid
// 2Mx4N (per-wave 64x32 per matrix) -> 96 MFMA/SIMD/barrier, 1.36x less
// LDS traffic per output than the 64x128 version.  Register prefetch PF1.
// GATHER: rows via tok[] (MoE, blockIdx.z=expert, compact output rows).
// ---------------------------------------------------------------------------
template<bool GATHER>
__global__ __launch_bounds__(512) void ffn_fusedp(
    const unsigned short* __restrict__ Ahi, const unsigned short* __restrict__ Alo,
    const unsigned short* __restrict__ W1hibase, const unsigned short* __restrict__ W1lobase,
    const unsigned short* __restrict__ W3hibase, const unsigned short* __restrict__ W3lobase,
    unsigned short* __restrict__ Thi, unsigned short* __restrict__ Tlo,
    int M, int N, int K,
    const int* __restrict__ tok, const int* __restrict__ counts,
    const int* __restrict__ offsets, size_t wstride)
{
    constexpr int TM = 128, TN = 128, PAD = 40;
    constexpr int FM = 4, FN = 2;

    int e = GATHER ? blockIdx.z : 0;
    int count = M, offs = 0;
    if (GATHER) {
        count = counts[e];
        offs  = offsets[e];
        if ((int)(blockIdx.y * TM) >= count) return;
    }
    const unsigned short* W1hi = W1hibase + (size_t)e * wstride;
    const unsigned short* W1lo = W1lobase + (size_t)e * wstride;
    const unsigned short* W3hi = W3hibase + (size_t)e * wstride;
    const unsigned short* W3lo = W3lobase + (size_t)e * wstride;

    __shared__ __align__(16) unsigned short Ah[TM][PAD];
    __shared__ __align__(16) unsigned short Al[TM][PAD];
    __shared__ __align__(16) unsigned short B1h[TN][PAD];
    __shared__ __align__(16) unsigned short B1l[TN][PAD];
    __shared__ __align__(16) unsigned short B3h[TN][PAD];
    __shared__ __align__(16) unsigned short B3l[TN][PAD];
    __shared__ int sTok[TM];

    int tid = threadIdx.x;
    int m0 = blockIdx.y * TM, n0 = blockIdx.x * TN;

    if (GATHER) {
        if (tid < TM) {
            int r = m0 + tid;
            sTok[tid] = (r < count) ? tok[offs + r] : tok[offs];
        }
        __syncthreads();
    }

    int srow = tid >> 2;          // 0..127 (one pass covers all 128 rows)
    int scol = (tid & 3) * 8;
    int wave = tid >> 6, lane = tid & 63;
    int wm = wave >> 2, wn = wave & 3;   // 2 x 4 wave grid
    int quad = lane >> 4, l16 = lane & 15;

    f32x4 accg[FM][FN], accu[FM][FN];
#pragma unroll
    for (int mi = 0; mi < FM; ++mi)
#pragma unroll
        for (int ni = 0; ni < FN; ++ni) {
            accg[mi][ni] = (f32x4){0.f, 0.f, 0.f, 0.f};
            accu[mi][ni] = (f32x4){0.f, 0.f, 0.f, 0.f};
        }

    size_t arow;
    if (GATHER) arow = (size_t)sTok[srow] * K;
    else        arow = (size_t)(m0 + srow) * K;
    size_t brow = (size_t)(n0 + srow) * K;

    ushort8v pah, pal, p1h, p1l, p3h, p3l;
    pah = *(const ushort8v*)(Ahi + arow + scol);
    pal = *(const ushort8v*)(Alo + arow + scol);
    p1h = *(const ushort8v*)(W1hi + brow + scol);
    p1l = *(const ushort8v*)(W1lo + brow + scol);
    p3h = *(const ushort8v*)(W3hi + brow + scol);
    p3l = *(const ushort8v*)(W3lo + brow + scol);

    for (int k0 = 0; k0 < K; k0 += 32) {
        *(ushort8v*)&Ah[srow][scol]  = pah;
        *(ushort8v*)&Al[srow][scol]  = pal;
        *(ushort8v*)&B1h[srow][scol] = p1h;
        *(ushort8v*)&B1l[srow][scol] = p1l;
        *(ushort8v*)&B3h[srow][scol] = p3h;
        *(ushort8v*)&B3l[srow][scol] = p3l;
        __syncthreads();
        if (k0 + 32 < K) {
            int kn = k0 + 32;
            pah = *(const ushort8v*)(Ahi + arow + kn + scol);
            pal = *(const ushort8v*)(Alo + arow + kn + scol);
            p1h = *(const ushort8v*)(W1hi + brow + kn + scol);
            p1l = *(const ushort8v*)(W1lo + brow + kn + scol);
            p3h = *(const ushort8v*)(W3hi + brow + kn + scol);
            p3l = *(const ushort8v*)(W3lo + brow + kn + scol);
        }

        bf16x8 ah[FM], al[FM];
#pragma unroll
        for (int mi = 0; mi < FM; ++mi) {
            ah[mi] = *(const bf16x8*)&Ah[wm * 64 + mi * 16 + l16][quad * 8];
            al[mi] = *(const bf16x8*)&Al[wm * 64 + mi * 16 + l16][quad * 8];
        }
        // gate = A @ W1^T
        {
            bf16x8 bh[FN], bl[FN];
#pragma unroll
            for (int ni = 0; ni < FN; ++ni) {
                bh[ni] = *(const bf16x8*)&B1h[wn * 32 + ni * 16 + l16][quad * 8];
                bl[ni] = *(const bf16x8*)&B1l[wn * 32 + ni * 16 + l16][quad * 8];
            }
#pragma unroll
            for (int mi = 0; mi < FM; ++mi)
#pragma unroll
                for (int ni = 0; ni < FN; ++ni) {
                    accg[mi][ni] = __builtin_amdgcn_mfma_f32_16x16x32_bf16(
                        ah[mi], bh[ni], accg[mi][ni], 0, 0, 0);
                    accg[mi][ni] = __builtin_amdgcn_mfma_f32_16x16x32_bf16(
                        al[mi], bh[ni], accg[mi][ni], 0, 0, 0);
                    accg[mi][ni] = __builtin_amdgcn_mfma_f32_16x16x32_bf16(
                        ah[mi], bl[ni], accg[mi][ni], 0, 0, 0);
                }
        }
        // up = A @ W3^T
        {
            bf16x8 bh[FN], bl[FN];
#pragma unroll
            for (int ni = 0; ni < FN; ++ni) {
                bh[ni] = *(const bf16x8*)&B3h[wn * 32 + ni * 16 + l16][quad * 8];
                bl[ni] = *(const bf16x8*)&B3l[wn * 32 + ni * 16 + l16][quad * 8];
            }
#pragma unroll
            for (int mi = 0; mi < FM; ++mi)
#pragma unroll
                for (int ni = 0; ni < FN; ++ni) {
                    accu[mi][ni] = __builtin_amdgcn_mfma_f32_16x16x32_bf16(
                        ah[mi], bh[ni], accu[mi][ni], 0, 0, 0);
                    accu[mi][ni] = __builtin_amdgcn_mfma_f32_16x16x32_bf16(
                        al[mi], bh[ni], accu[mi][ni], 0, 0, 0);
                    accu[mi][ni] = __builtin_amdgcn_mfma_f32_16x16x32_bf16(
                        ah[mi], bl[ni], accu[mi][ni], 0, 0, 0);
                }
        }
        __syncthreads();
    }

#pragma unroll
    for (int mi = 0; mi < FM; ++mi) {
#pragma unroll
        for (int ni = 0; ni < FN; ++ni) {
            int col = n0 + wn * 32 + ni * 16 + l16;
#pragma unroll
            for (int r = 0; r < 4; ++r) {
                int row = wm * 64 + mi * 16 + quad * 4 + r;
                float g = accg[mi][ni][r];
                float u = accu[mi][ni][r];
                float t = (g / (1.0f + expf(-g))) * u;
                unsigned short th, tl;
                splitbf(t, th, tl);
                if (GATHER) {
                    int rr = m0 + row;
                    if (rr < count) {
                        size_t idx = (size_t)(offs + rr) * N + col;
                        Thi[idx] = th; Tlo[idx] = tl;
                    }
                } else {
                    size_t idx = (size_t)(m0 + row) * N + col;
                    Thi[idx] = th; Tlo[idx] = tl;
                }
            }
        }
    }
}

// ---------------------------------------------------------------------------
// RoPE in-place over q,k slices of qkv [N, 3*D]
// ---------------------------------------------------------------------------
__global__ __launch_bounds__(256) void rope_kernel(float* __restrict__ qkv)
{
    const int HD2 = HDc / 2;
    int idx = blockIdx.x * blockDim.x + threadIdx.x;
    int total = Nc * NHc * HD2;
    if (idx >= total) return;
    int i = idx % HD2;
    int hh = (idx / HD2) % NHc;
    int n = idx / (HD2 * NHc);
    int t = n % Tc;
    float invf = expf(-(2.0f * (float)i / (float)HDc) * logf(10000.0f));
    float f = (float)t * invf;
    float c = cosf(f), s = sinf(f);
    size_t base = (size_t)n * (3 * Dc) + (size_t)hh * HDc;
    float* qp = qkv + base;
    float* kp = qkv + base + Dc;
    float q1 = qp[i], q2 = qp[i + HD2];
    qp[i]       = q1 * c - q2 * s;
    qp[i + HD2] = q1 * s + q2 * c;
    float k1 = kp[i], k2 = kp[i + HD2];
    kp[i]       = k1 * c - k2 * s;
    kp[i + HD2] = k1 * s + k2 * c;
}

// ---------------------------------------------------------------------------
// MFMA flash attention, bf16x3 precision.  Emits output PRE-SPLIT (hi/lo)
// for the out-projection GEMM.
// ---------------------------------------------------------------------------
__global__ __launch_bounds__(256) void attn_mfma(
    const float* __restrict__ qkv, unsigned short* __restrict__ outh,
    unsigned short* __restrict__ outl)
{
    constexpr int PAD = 72;
    __shared__ __align__(16) unsigned short Qh[64][PAD];
    __shared__ __align__(16) unsigned short Ql[64][PAD];
    __shared__ __align__(16) unsigned short Kh[64][PAD];   // aliased: P-hi
    __shared__ __align__(16) unsigned short Kl[64][PAD];   // aliased: P-lo
    __shared__ __align__(16) unsigned short Vth[64][PAD];  // V^T [hd][kv]
    __shared__ __align__(16) unsigned short Vtl[64][PAD];

    int qb = blockIdx.x, bh = blockIdx.y;
    int b = bh >> 3, hh = bh & 7;
    const int D3 = 3 * Dc;
    const float* base = qkv + (size_t)b * Tc * D3 + (size_t)hh * HDc;

    int tid = threadIdx.x;
    int wave = tid >> 6, lane = tid & 63;
    int quad = lane >> 4, l16 = lane & 15;

    int srow = tid >> 2;
    int scb  = (tid & 3) * 16;
    int vhd  = lane;
    int vkb  = wave * 16;

    {
        const float* qp = base + (size_t)(qb * 64 + srow) * D3 + scb;
        float4 q0 = *(const float4*)(qp);
        float4 q1 = *(const float4*)(qp + 4);
        float4 q2 = *(const float4*)(qp + 8);
        float4 q3 = *(const float4*)(qp + 12);
        const float sc = 0.125f;
        q0.x *= sc; q0.y *= sc; q0.z *= sc; q0.w *= sc;
        q1.x *= sc; q1.y *= sc; q1.z *= sc; q1.w *= sc;
        q2.x *= sc; q2.y *= sc; q2.z *= sc; q2.w *= sc;
        q3.x *= sc; q3.y *= sc; q3.z *= sc; q3.w *= sc;
        unsigned short h, l;
        ushort8v hv, lv;
        splitbf(q0.x, h, l); hv[0] = h; lv[0] = l;
        splitbf(q0.y, h, l); hv[1] = h; lv[1] = l;
        splitbf(q0.z, h, l); hv[2] = h; lv[2] = l;
        splitbf(q0.w, h, l); hv[3] = h; lv[3] = l;
        splitbf(q1.x, h, l); hv[4] = h; lv[4] = l;
        splitbf(q1.y, h, l); hv[5] = h; lv[5] = l;
        splitbf(q1.z, h, l); hv[6] = h; lv[6] = l;
        splitbf(q1.w, h, l); hv[7] = h; lv[7] = l;
        *(ushort8v*)&Qh[srow][scb]     = hv;
        *(ushort8v*)&Ql[srow][scb]     = lv;
        splitbf(q2.x, h, l); hv[0] = h; lv[0] = l;
        splitbf(q2.y, h, l); hv[1] = h; lv[1] = l;
        splitbf(q2.z, h, l); hv[2] = h; lv[2] = l;
        splitbf(q2.w, h, l); hv[3] = h; lv[3] = l;
        splitbf(q3.x, h, l); hv[4] = h; lv[4] = l;
        splitbf(q3.y, h, l); hv[5] = h; lv[5] = l;
        splitbf(q3.z, h, l); hv[6] = h; lv[6] = l;
        splitbf(q3.w, h, l); hv[7] = h; lv[7] = l;
        *(ushort8v*)&Qh[srow][scb + 8] = hv;
        *(ushort8v*)&Ql[srow][scb + 8] = lv;
    }
    __syncthreads();
    bf16x8 qah[2], qal[2];
#pragma unroll
    for (int ks = 0; ks < 2; ++ks) {
        qah[ks] = *(const bf16x8*)&Qh[wave * 16 + l16][ks * 32 + quad * 8];
        qal[ks] = *(const bf16x8*)&Ql[wave * 16 + l16][ks * 32 + quad * 8];
    }

    float4 kf0, kf1, kf2, kf3;
    float vf[16];
    {
        const float* kp = base + (size_t)srow * D3 + Dc + scb;
        kf0 = *(const float4*)(kp);
        kf1 = *(const float4*)(kp + 4);
        kf2 = *(const float4*)(kp + 8);
        kf3 = *(const float4*)(kp + 12);
        const float* vp = base + (size_t)vkb * D3 + 2 * Dc + vhd;
#pragma unroll
        for (int i = 0; i < 16; ++i) vf[i] = vp[(size_t)i * D3];
    }

    f32x4 o[4];
#pragma unroll
    for (int f = 0; f < 4; ++f) o[f] = (f32x4){0.f, 0.f, 0.f, 0.f};
    float mrow[4], lrow[4];
#pragma unroll
    for (int r = 0; r < 4; ++r) { mrow[r] = -1e30f; lrow[r] = 0.0f; }

    for (int kt = 0; kt <= qb; ++kt) {
        __syncthreads();
        {
            unsigned short h, l;
            ushort8v hv, lv;
            splitbf(kf0.x, h, l); hv[0] = h; lv[0] = l;
            splitbf(kf0.y, h, l); hv[1] = h; lv[1] = l;
            splitbf(kf0.z, h, l); hv[2] = h; lv[2] = l;
            splitbf(kf0.w, h, l); hv[3] = h; lv[3] = l;
            splitbf(kf1.x, h, l); hv[4] = h; lv[4] = l;
            splitbf(kf1.y, h, l); hv[5] = h; lv[5] = l;
            splitbf(kf1.z, h, l); hv[6] = h; lv[6] = l;
            splitbf(kf1.w, h, l); hv[7] = h; lv[7] = l;
            *(ushort8v*)&Kh[srow][scb]     = hv;
            *(ushort8v*)&Kl[srow][scb]     = lv;
            splitbf(kf2.x, h, l); hv[0] = h; lv[0] = l;
            splitbf(kf2.y, h, l); hv[1] = h; lv[1] = l;
            splitbf(kf2.z, h, l); hv[2] = h; lv[2] = l;
            splitbf(kf2.w, h, l); hv[3] = h; lv[3] = l;
            splitbf(kf3.x, h, l); hv[4] = h; lv[4] = l;
            splitbf(kf3.y, h, l); hv[5] = h; lv[5] = l;
            splitbf(kf3.z, h, l); hv[6] = h; lv[6] = l;
            splitbf(kf3.w, h, l); hv[7] = h; lv[7] = l;
            *(ushort8v*)&Kh[srow][scb + 8] = hv;
            *(ushort8v*)&Kl[srow][scb + 8] = lv;
        }
        {
            unsigned short h, l;
            ushort8v hv, lv;
#pragma unroll
            for (int i = 0; i < 8; ++i) {
                splitbf(vf[i], h, l); hv[i] = h; lv[i] = l;
            }
            *(ushort8v*)&Vth[vhd][vkb]     = hv;
            *(ushort8v*)&Vtl[vhd][vkb]     = lv;
#pragma unroll
            for (int i = 0; i < 8; ++i) {
                splitbf(vf[8 + i], h, l); hv[i] = h; lv[i] = l;
            }
            *(ushort8v*)&Vth[vhd][vkb + 8] = hv;
            *(ushort8v*)&Vtl[vhd][vkb + 8] = lv;
        }
        __syncthreads();
        if (kt < qb) {
            const float* kp = base + (size_t)((kt + 1) * 64 + srow) * D3 + Dc + scb;
            kf0 = *(const float4*)(kp);
            kf1 = *(const float4*)(kp + 4);
            kf2 = *(const float4*)(kp + 8);
            kf3 = *(const float4*)(kp + 12);
            const float* vp = base + (size_t)((kt + 1) * 64 + vkb) * D3 + 2 * Dc + vhd;
#pragma unroll
            for (int i = 0; i < 16; ++i) vf[i] = vp[(size_t)i * D3];
        }

        f32x4 s[4];
#pragma unroll
        for (int ni = 0; ni < 4; ++ni) s[ni] = (f32x4){0.f, 0.f, 0.f, 0.f};
#pragma unroll
        for (int ks = 0; ks < 2; ++ks) {
            bf16x8 kh_[4], kl_[4];
#pragma unroll
            for (int ni = 0; ni < 4; ++ni) {
                kh_[ni] = *(const bf16x8*)&Kh[ni * 16 + l16][ks * 32 + quad * 8];
                kl_[ni] = *(const bf16x8*)&Kl[ni * 16 + l16][ks * 32 + quad * 8];
            }
#pragma unroll
            for (int ni = 0; ni < 4; ++ni) {
                s[ni] = __builtin_amdgcn_mfma_f32_16x16x32_bf16(
                    qah[ks], kh_[ni], s[ni], 0, 0, 0);
                s[ni] = __builtin_amdgcn_mfma_f32_16x16x32_bf16(
                    qal[ks], kh_[ni], s[ni], 0, 0, 0);
                s[ni] = __builtin_amdgcn_mfma_f32_16x16x32_bf16(
                    qah[ks], kl_[ni], s[ni], 0, 0, 0);
            }
        }

        if (kt == qb) {
#pragma unroll
            for (int ni = 0; ni < 4; ++ni)
#pragma unroll
                for (int r = 0; r < 4; ++r)
                    if (ni * 16 + l16 > wave * 16 + quad * 4 + r)
                        s[ni][r] = -1e30f;
        }

        float al4[4];
#pragma unroll
        for (int r = 0; r < 4; ++r) {
            float rm = fmaxf(fmaxf(s[0][r], s[1][r]), fmaxf(s[2][r], s[3][r]));
            rm = fmaxf(rm, __shfl_xor(rm, 1));
            rm = fmaxf(rm, __shfl_xor(rm, 2));
            rm = fmaxf(rm, __shfl_xor(rm, 4));
            rm = fmaxf(rm, __shfl_xor(rm, 8));
            float mn = fmaxf(mrow[r], rm);
            al4[r] = __expf(mrow[r] - mn);
            mrow[r] = mn;
            float rs = 0.0f;
#pragma unroll
            for (int ni = 0; ni < 4; ++ni) {
                float pv = __expf(s[ni][r] - mn);
                s[ni][r] = pv;
                rs += pv;
            }
            rs += __shfl_xor(rs, 1);
            rs += __shfl_xor(rs, 2);
            rs += __shfl_xor(rs, 4);
            rs += __shfl_xor(rs, 8);
            lrow[r] = lrow[r] * al4[r] + rs;
        }

        __syncthreads();
#pragma unroll
        for (int ni = 0; ni < 4; ++ni)
#pragma unroll
            for (int r = 0; r < 4; ++r) {
                unsigned short hp, lp;
                splitbf(s[ni][r], hp, lp);
                Kh[wave * 16 + quad * 4 + r][ni * 16 + l16] = hp;
                Kl[wave * 16 + quad * 4 + r][ni * 16 + l16] = lp;
            }
#pragma unroll
        for (int f = 0; f < 4; ++f)
#pragma unroll
            for (int r = 0; r < 4; ++r)
                o[f][r] *= al4[r];
#pragma unroll
        for (int ks = 0; ks < 2; ++ks) {
            bf16x8 pah = *(const bf16x8*)&Kh[wave * 16 + l16][ks * 32 + quad * 8];
            bf16x8 pal = *(const bf16x8*)&Kl[wave * 16 + l16][ks * 32 + quad * 8];
#pragma unroll
            for (int f = 0; f < 4; ++f) {
                bf16x8 vh_ = *(const bf16x8*)&Vth[f * 16 + l16][ks * 32 + quad * 8];
                bf16x8 vl_ = *(const bf16x8*)&Vtl[f * 16 + l16][ks * 32 + quad * 8];
                o[f] = __builtin_amdgcn_mfma_f32_16x16x32_bf16(
                    pah, vh_, o[f], 0, 0, 0);
                o[f] = __builtin_amdgcn_mfma_f32_16x16x32_bf16(
                    pal, vh_, o[f], 0, 0, 0);
                o[f] = __builtin_amdgcn_mfma_f32_16x16x32_bf16(
                    pah, vl_, o[f], 0, 0, 0);
            }
        }
    }

#pragma unroll
    for (int r = 0; r < 4; ++r) {
        float inv = 1.0f / lrow[r];
        int q = qb * 64 + wave * 16 + quad * 4 + r;
#pragma unroll
        for (int f = 0; f < 4; ++f) {
            size_t idx = (size_t)(b * Tc + q) * Dc + hh * HDc + f * 16 + l16;
            unsigned short hp, lp;
            splitbf(o[f][r] * inv, hp, lp);
            outh[idx] = hp; outl[idx] = lp;
        }
    }
}

// ---------------------------------------------------------------------------
// Router logits: one wave per token
// ---------------------------------------------------------------------------
__global__ __launch_bounds__(64) void router_kernel(
    const float* __restrict__ x, const float* __restrict__ rw,
    float* __restrict__ logits)
{
    int n = blockIdx.x;
    int lane = threadIdx.x;
    const float* xr = x + (size_t)n * Dc;
    for (int e = 0; e < Ec; ++e) {
        const float* wr = rw + (size_t)e * Dc;
        float p = 0.0f;
        for (int d = lane; d < Dc; d += 64) p += xr[d] * wr[d];
        for (int off = 32; off > 0; off >>= 1) p += __shfl_down(p, off);
        if (lane == 0) logits[(size_t)n * Ec + e] = p;
    }
}

__global__ void zero8_kernel(int* __restrict__ counts)
{
    if (threadIdx.x < Ec) counts[threadIdx.x] = 0;
}

__global__ __launch_bounds__(256) void topk_count_kernel(
    const float* __restrict__ logits, int* __restrict__ counts,
    int2* __restrict__ eidx, float2* __restrict__ ewt)
{
    int n = blockIdx.x * blockDim.x + threadIdx.x;
    if (n >= Nc) return;
    const float* lg = logits + (size_t)n * Ec;
    int i0 = -1, i1 = -1;
    float v0 = -1e30f, v1 = -1e30f;
    for (int e = 0; e < Ec; ++e) {
        float v = lg[e];
        if (v > v0) { v1 = v0; i1 = i0; v0 = v; i0 = e; }
        else if (v > v1) { v1 = v; i1 = e; }
    }
    float e1 = expf(v1 - v0);
    float w0 = 1.0f / (1.0f + e1);
    float w1 = e1 / (1.0f + e1);
    atomicAdd(&counts[i0], 1);
    atomicAdd(&counts[i1], 1);
    eidx[n] = make_int2(i0, i1);
    ewt[n]  = make_float2(w0, w1);
}

__global__ void scan_kernel(int* __restrict__ counts, int* __restrict__ offsets)
{
    if (threadIdx.x == 0) {
        int s = 0;
        for (int e = 0; e < Ec; ++e) { offsets[e] = s; s += counts[e]; counts[e] = 0; }
    }
}

__global__ __launch_bounds__(256) void topk_place_kernel(
    const int2* __restrict__ eidx, const float2* __restrict__ ewt,
    int* __restrict__ counts, const int* __restrict__ offsets,
    int* __restrict__ tok, float* __restrict__ twt)
{
    int n = blockIdx.x * blockDim.x + threadIdx.x;
    if (n >= Nc) return;
    int2 ei = eidx[n];
    float2 w = ewt[n];
    int p0 = atomicAdd(&counts[ei.x], 1);
    int r0 = offsets[ei.x] + p0;
    tok[r0] = n; twt[r0] = w.x;
    int p1 = atomicAdd(&counts[ei.y], 1);
    int r1 = offsets[ei.y] + p1;
    tok[r1] = n; twt[r1] = w.y;
}

// ---------------------------------------------------------------------------
// Host-side orchestration
// ---------------------------------------------------------------------------
extern "C" void kernel_launch(void* const* d_in, const int* in_sizes, int n_in,
                              void* d_out, int out_size, void* d_ws, size_t ws_size,
                              hipStream_t stream)
{
    const float* x        = (const float*)d_in[0];
    const float* qkv_w    = (const float*)d_in[1];
    const float* out_w    = (const float*)d_in[2];
    const float* norm1_w  = (const float*)d_in[3];
    const float* norm2_w  = (const float*)d_in[4];
    const float* router_w = (const float*)d_in[5];
    const float* moe_w1   = (const float*)d_in[6];
    const float* moe_w2   = (const float*)d_in[7];
    const float* moe_w3   = (const float*)d_in[8];
    const float* f_w1     = (const float*)d_in[9];
    const float* f_w2     = (const float*)d_in[10];
    const float* f_w3     = (const float*)d_in[11];
    const float* norm_f   = (const float*)d_in[12];
    float* out = (float*)d_out;

    // workspace (~118 MB)
    float* p = (float*)d_ws;
    float* h      = p;  p += Nc * Dc;
    float* xn     = p;  p += Nc * Dc;
    unsigned short* xnh = (unsigned short*)p;  p += Nc * Dc / 2;
    unsigned short* xnl = (unsigned short*)p;  p += Nc * Dc / 2;
    float* arena  = p;  p += (size_t)NKc * Hc;   // qkv fp32 OR t hi+lo
    float* logits = p;  p += Nc * Ec;
    int*   counts  = (int*)p;  p += 16;
    int*   offsets = (int*)p;  p += 16;
    int2*  eidx    = (int2*)p; p += 2 * Nc;
    float* ewt     = p;        p += 2 * Nc;
    int*   tok     = (int*)p;  p += NKc;
    float* twt     = p;        p += NKc;
    // pre-split weight buffers (ushort counts)
    unsigned short* wqh = (unsigned short*)p;
    unsigned short* wql = wqh + (size_t)3 * Dc * Dc;
    unsigned short* woh = wql + (size_t)3 * Dc * Dc;
    unsigned short* wol = woh + (size_t)Dc * Dc;
    unsigned short* wah = wol + (size_t)Dc * Dc;          // w1 / later w2
    unsigned short* wal = wah + (size_t)Ec * Hc * Dc;
    unsigned short* wbh = wal + (size_t)Ec * Hc * Dc;     // w3
    unsigned short* wbl = wbh + (size_t)Ec * Hc * Dc;

    float* qkv = arena;                         // [Nc][3*Dc] fp32, attn phase
    unsigned short* th = (unsigned short*)arena;         // t hi, FFN phase
    unsigned short* tl = th + (size_t)NKc * Hc;          // t lo

    hipMemcpyAsync(h, x, (size_t)Nc * Dc * sizeof(float),
                   hipMemcpyDeviceToDevice, stream);

    for (int l = 0; l < Lc; ++l) {
        // --- attention block ---
        {
            int n4 = 3 * Dc * Dc / 4;
            split_w_kernel<<<(n4 + 255) / 256, 256, 0, stream>>>(
                qkv_w + (size_t)l * 3 * Dc * Dc, wqh, wql, n4);
        }
        rmsnorm_split_kernel<<<Nc, 256, 0, stream>>>(
            h, norm1_w + (size_t)l * Dc, xn, xnh, xnl);
        gemm3p<0, 64, 128, 1><<<dim3(3 * Dc / 128, Nc / 64, 1), 256, 0, stream>>>(
            xnh, xnl, wqh, wql, qkv, Nc, 3 * Dc, Dc,
            nullptr, nullptr, nullptr, nullptr, 0);
        {
            int total = Nc * NHc * (HDc / 2);
            rope_kernel<<<(total + 255) / 256, 256, 0, stream>>>(qkv);
        }
        {
            int n4 = Dc * Dc / 4;
            split_w_kernel<<<(n4 + 255) / 256, 256, 0, stream>>>(
                out_w + (size_t)l * Dc * Dc, woh, wol, n4);
        }
        attn_mfma<<<dim3(Tc / 64, Bc * NHc), 256, 0, stream>>>(qkv, xnh, xnl);
        // attn-out projection: split-K2, atomic accumulate into h (residual)
        gemm3p<2, 64, 64, 2><<<dim3(Dc / 64, Nc / 64, 2), 256, 0, stream>>>(
            xnh, xnl, woh, wol, h, Nc, Dc, Dc,
            nullptr, nullptr, nullptr, nullptr, 0);

        // --- FFN block ---
        rmsnorm_split_kernel<<<Nc, 256, 0, stream>>>(
            h, norm2_w + (size_t)l * Dc, xn, xnh, xnl);
        if (l == 0 || l == 2) {
            int m = l / 2;
            router_kernel<<<Nc, 64, 0, stream>>>(
                xn, router_w + (size_t)m * Ec * Dc, logits);
            zero8_kernel<<<1, 64, 0, stream>>>(counts);
            topk_count_kernel<<<Nc / 256, 256, 0, stream>>>(
                logits, counts, eidx, (float2*)ewt);
            scan_kernel<<<1, 64, 0, stream>>>(counts, offsets);
            topk_place_kernel<<<Nc / 256, 256, 0, stream>>>(
                eidx, (float2*)ewt, counts, offsets, tok, twt);

            int n4 = Ec * Hc * Dc / 4;
            split_w_kernel<<<(n4 + 255) / 256, 256, 0, stream>>>(
                moe_w1 + (size_t)m * Ec * Hc * Dc, wah, wal, n4);
            split_w_kernel<<<(n4 + 255) / 256, 256, 0, stream>>>(
                moe_w3 + (size_t)m * Ec * Hc * Dc, wbh, wbl, n4);
            ffn_fusedp<true><<<dim3(Hc / 128, NKc / 128, Ec), 512, 0, stream>>>(
                xnh, xnl, wah, wal, wbh, wbl, th, tl, Nc, Hc, Dc,
                tok, counts, offsets, (size_t)Hc * Dc);
            split_w_kernel<<<(n4 + 255) / 256, 256, 0, stream>>>(
                moe_w2 + (size_t)m * Ec * Dc * Hc, wah, wal, n4);
            // MoE down: split-K2 (z = expert*2 + k-half), atomic scatter
            gemm3p<5, 64, 128, 2><<<dim3(Dc / 128, NKc / 64, Ec * 2), 256, 0, stream>>>(
                th, tl, wah, wal, h, Nc, Dc, Hc,
                tok, twt, counts, offsets, (size_t)Dc * Hc);
        } else {
            int m = (l - 1) / 2;
            int n4 = Hc * Dc / 4;
            split_w_kernel<<<(n4 + 255) / 256, 256, 0, stream>>>(
                f_w1 + (size_t)m * Hc * Dc, wah, wal, n4);
            split_w_kernel<<<(n4 + 255) / 256, 256, 0, stream>>>(
                f_w3 + (size_t)m * Hc * Dc, wbh, wbl, n4);
            ffn_fusedp<false><<<dim3(Hc / 128, Nc / 128, 1), 512, 0, stream>>>(
                xnh, xnl, wah, wal, wbh, wbl, th, tl, Nc, Hc, Dc,
                nullptr, nullptr, nullptr, 0);
            split_w_kernel<<<(n4 + 255) / 256, 256, 0, stream>>>(
                f_w2 + (size_t)m * Dc * Hc, wah, wal, n4);
            // dense down: split-K2, atomic accumulate into h (residual)
            gemm3p<2, 64, 128, 2><<<dim3(Dc / 128, Nc / 64, 2), 256, 0, stream>>>(
                th, tl, wah, wal, h, Nc, Dc, Hc,
                nullptr, nullptr, nullptr, nullptr, 0);
        }
    }

    rmsnorm_kernel<<<Nc, 256, 0, stream>>>(h, norm_f, out);
}